// Round 1
// baseline (385.873 us; speedup 1.0000x reference)
//
#include <hip/hip_runtime.h>
#include <math.h>

#define CC 128   // channels
#define NN 1024  // H*W
#define NT 64    // n-tile per GEMM block
#define BTOT 32  // B*T

// ---------- helpers ----------
__device__ __forceinline__ void gemm_pass(const float (*xs)[NT],
                                          const float* __restrict__ W,
                                          const float* __restrict__ bias,
                                          int o0, int nn, float acc[8][4]) {
#pragma unroll
    for (int r = 0; r < 8; ++r) {
        float b = bias[o0 + r];
#pragma unroll
        for (int j = 0; j < 4; ++j) acc[r][j] = b;
    }
    for (int c = 0; c < CC; c += 4) {
        float4 x0 = *(const float4*)&xs[c + 0][nn];
        float4 x1 = *(const float4*)&xs[c + 1][nn];
        float4 x2 = *(const float4*)&xs[c + 2][nn];
        float4 x3 = *(const float4*)&xs[c + 3][nn];
#pragma unroll
        for (int r = 0; r < 8; ++r) {
            float4 w = *(const float4*)(W + (o0 + r) * CC + c);
            acc[r][0] += w.x * x0.x + w.y * x1.x + w.z * x2.x + w.w * x3.x;
            acc[r][1] += w.x * x0.y + w.y * x1.y + w.z * x2.y + w.w * x3.y;
            acc[r][2] += w.x * x0.z + w.y * x1.z + w.z * x2.z + w.w * x3.z;
            acc[r][3] += w.x * x0.w + w.y * x1.w + w.z * x2.w + w.w * x3.w;
        }
    }
}

__device__ __forceinline__ void store_on(float* dst, int o0, int nn, const float acc[8][4]) {
    // dst pre-offset to [bt][*][n0]; layout [o][n]
#pragma unroll
    for (int r = 0; r < 8; ++r) {
        float4 v;
        v.x = acc[r][0]; v.y = acc[r][1]; v.z = acc[r][2]; v.w = acc[r][3];
        *(float4*)(dst + (size_t)(o0 + r) * NN + nn) = v;
    }
}

__device__ __forceinline__ void store_tr(float* dst, int o0, int nn, const float acc[8][4]) {
    // dst pre-offset to (bt*NN + n0)*CC; layout [n][c]
#pragma unroll
    for (int j = 0; j < 4; ++j) {
        float4 lo, hi;
        lo.x = acc[0][j]; lo.y = acc[1][j]; lo.z = acc[2][j]; lo.w = acc[3][j];
        hi.x = acc[4][j]; hi.y = acc[5][j]; hi.z = acc[6][j]; hi.w = acc[7][j];
        *(float4*)(dst + (size_t)(nn + j) * CC + o0) = lo;
        *(float4*)(dst + (size_t)(nn + j) * CC + o0 + 4) = hi;
    }
}

// ---------- kernel 1: ef/df projection + cosine sim + L2 norm ----------
__global__ __launch_bounds__(256) void k_proj(
    const float* __restrict__ edge, const float* __restrict__ dvs,
    const float* __restrict__ We, const float* __restrict__ be,
    const float* __restrict__ Wd, const float* __restrict__ bd,
    float* __restrict__ ef, float* __restrict__ df,
    float* __restrict__ l2e, float* __restrict__ sim)
{
    __shared__ float xe[CC][NT];
    __shared__ float xd[CC][NT];
    __shared__ float st2e[16][NT];
    __shared__ float st2d[16][NT];
    __shared__ float sted[16][NT];
    const int t = threadIdx.x;
    const int bt = blockIdx.y;
    const int n0 = blockIdx.x * NT;
    const size_t base = (size_t)bt * CC * NN + n0;
    {
        int r = t >> 4;
        const int c4 = (t & 15) * 4;
        for (int i = 0; i < 8; ++i, r += 16) {
            *(float4*)&xe[r][c4] = *(const float4*)(edge + base + (size_t)r * NN + c4);
            *(float4*)&xd[r][c4] = *(const float4*)(dvs + base + (size_t)r * NN + c4);
        }
    }
    __syncthreads();
    const int oi = t >> 4, ni = t & 15;
    const int o0 = oi * 8, nn = ni * 4;
    float accE[8][4], accD[8][4];
    gemm_pass(xe, We, be, o0, nn, accE);
    gemm_pass(xd, Wd, bd, o0, nn, accD);
    store_on(ef + base, o0, nn, accE);
    store_on(df + base, o0, nn, accD);
    // per-position stats over channels
    float p2e[4] = {0, 0, 0, 0}, p2d[4] = {0, 0, 0, 0}, ped[4] = {0, 0, 0, 0};
#pragma unroll
    for (int r = 0; r < 8; ++r)
#pragma unroll
        for (int j = 0; j < 4; ++j) {
            p2e[j] += accE[r][j] * accE[r][j];
            p2d[j] += accD[r][j] * accD[r][j];
            ped[j] += accE[r][j] * accD[r][j];
        }
#pragma unroll
    for (int j = 0; j < 4; ++j) {
        st2e[oi][nn + j] = p2e[j];
        st2d[oi][nn + j] = p2d[j];
        sted[oi][nn + j] = ped[j];
    }
    __syncthreads();
    if (t < NT) {
        float s2e = 0.f, s2d = 0.f, sed = 0.f;
#pragma unroll
        for (int i = 0; i < 16; ++i) {
            s2e += st2e[i][t];
            s2d += st2d[i][t];
            sed += sted[i][t];
        }
        float le = sqrtf(s2e), ld = sqrtf(s2d);
        float sm = (sed / ((le + 1e-6f) * (ld + 1e-6f)) + 1.0f) * 0.5f;
        l2e[(size_t)bt * NN + n0 + t] = le;
        sim[(size_t)bt * NN + n0 + t] = sm;
    }
}

// ---------- kernel 2: spatial softmax of l2e -> density ----------
__global__ __launch_bounds__(256) void k_dens(const float* __restrict__ l2e,
                                              float* __restrict__ dens)
{
    __shared__ float red1[4];
    __shared__ float red2[4];
    const int bt = blockIdx.x, t = threadIdx.x;
    const int lane = t & 63, wid = t >> 6;
    const float* x = l2e + (size_t)bt * NN;
    float v[4], m = -1e30f;
#pragma unroll
    for (int i = 0; i < 4; ++i) { v[i] = x[t + 256 * i]; m = fmaxf(m, v[i]); }
#pragma unroll
    for (int off = 32; off >= 1; off >>= 1) m = fmaxf(m, __shfl_xor(m, off));
    if (lane == 0) red1[wid] = m;
    __syncthreads();
    m = fmaxf(fmaxf(red1[0], red1[1]), fmaxf(red1[2], red1[3]));
    float e[4], s = 0.f;
#pragma unroll
    for (int i = 0; i < 4; ++i) { e[i] = expf(v[i] - m); s += e[i]; }
#pragma unroll
    for (int off = 32; off >= 1; off >>= 1) s += __shfl_xor(s, off);
    if (lane == 0) red2[wid] = s;
    __syncthreads();
    s = red2[0] + red2[1] + red2[2] + red2[3];
    const float scale = 1024.0f / s;
#pragma unroll
    for (int i = 0; i < 4; ++i) dens[(size_t)bt * NN + t + 256 * i] = e[i] * scale;
}

// ---------- kernel 3: gated q/k/v projections (k,v transposed) ----------
__global__ __launch_bounds__(256) void k_qkv(
    const float* __restrict__ ef, const float* __restrict__ df,
    const float* __restrict__ sim, const float* __restrict__ dens,
    const float* __restrict__ Wq, const float* __restrict__ bq,
    const float* __restrict__ Wk, const float* __restrict__ bk,
    const float* __restrict__ Wv, const float* __restrict__ bv,
    float* __restrict__ q, float* __restrict__ kT, float* __restrict__ vT)
{
    __shared__ float xq[CC][NT];
    __shared__ float xd2[CC][NT];
    const int t = threadIdx.x;
    const int bt = blockIdx.y;
    const int n0 = blockIdx.x * NT;
    const size_t base = (size_t)bt * CC * NN + n0;
    {
        int r = t >> 4;
        const int c4 = (t & 15) * 4;
        float4 sv = *(const float4*)(sim + (size_t)bt * NN + n0 + c4);
        float4 dv = *(const float4*)(dens + (size_t)bt * NN + n0 + c4);
        for (int i = 0; i < 8; ++i, r += 16) {
            float4 e4 = *(const float4*)(ef + base + (size_t)r * NN + c4);
            float4 d4 = *(const float4*)(df + base + (size_t)r * NN + c4);
            float4 a, b;
            a.x = e4.x * sv.x; a.y = e4.y * sv.y; a.z = e4.z * sv.z; a.w = e4.w * sv.w;
            b.x = d4.x * dv.x; b.y = d4.y * dv.y; b.z = d4.z * dv.z; b.w = d4.w * dv.w;
            *(float4*)&xq[r][c4] = a;
            *(float4*)&xd2[r][c4] = b;
        }
    }
    __syncthreads();
    const int oi = t >> 4, ni = t & 15;
    const int o0 = oi * 8, nn = ni * 4;
    float acc[8][4];
    gemm_pass(xq, Wq, bq, o0, nn, acc);
    store_on(q + base, o0, nn, acc);
    gemm_pass(xd2, Wk, bk, o0, nn, acc);
    store_tr(kT + ((size_t)bt * NN + n0) * CC, o0, nn, acc);
    gemm_pass(xd2, Wv, bv, o0, nn, acc);
    store_tr(vT + ((size_t)bt * NN + n0) * CC, o0, nn, acc);
}

// ---------- kernel 4: banded window attention ----------
__global__ __launch_bounds__(256) void k_attn(
    const float* __restrict__ q, const float* __restrict__ kT,
    const float* __restrict__ vT, float* __restrict__ attout)
{
    __shared__ float q_s[32][132];
    __shared__ float sc[224][33];
    __shared__ float red1[8][32];
    __shared__ float red2[8][32];
    const int t = threadIdx.x;
    const int qx = blockIdx.x;
    const int bt = blockIdx.y;
    // stage q tile: q_s[qy][c]
    {
        const float* qb = q + (size_t)bt * CC * NN + qx * 32;
        for (int idx = t; idx < 4096; idx += 256) {
            int c = idx >> 5, qy = idx & 31;
            q_s[qy][c] = qb[(size_t)c * NN + qy];
        }
    }
    __syncthreads();
    const int kxmin = max(qx - 3, 0), kxmax = min(qx + 3, 31);
    const int KN = (kxmax - kxmin + 1) * 32;
    const int qy = t & 31, kg = t >> 5;
    const float invsq = 0.08838834764831843f; // 1/sqrt(128)
    float lmax = -1e30f;
    for (int kidx = kg; kidx < KN; kidx += 8) {
        const int kx = kxmin + (kidx >> 5);
        const int ky = kidx & 31;
        const int kn = (kx << 5) | ky;
        const float4* kp = (const float4*)(kT + ((size_t)bt * NN + kn) * CC);
        float acc = 0.f;
        for (int c4 = 0; c4 < 32; ++c4) {
            float4 kv = kp[c4];
            float4 qv = *(const float4*)&q_s[qy][c4 * 4];
            acc += kv.x * qv.x + kv.y * qv.y + kv.z * qv.z + kv.w * qv.w;
        }
        float s = acc * invsq;
        int d = ky - qy;
        if (d < -3 || d > 3) s -= 10000.0f;
        sc[kidx][qy] = s;
        lmax = fmaxf(lmax, s);
    }
    red1[kg][qy] = lmax;
    __syncthreads();
    float m = red1[0][qy];
#pragma unroll
    for (int i = 1; i < 8; ++i) m = fmaxf(m, red1[i][qy]);
    float lsum = 0.f;
    for (int kidx = kg; kidx < KN; kidx += 8) {
        float e = expf(sc[kidx][qy] - m);
        sc[kidx][qy] = e;
        lsum += e;
    }
    red2[kg][qy] = lsum;
    __syncthreads();
    float ssum = 0.f;
#pragma unroll
    for (int i = 0; i < 8; ++i) ssum += red2[i][qy];
    const float inv = 1.0f / ssum;
    // PV: thread owns (qy, 16 channels)
    const int c0 = kg * 16;
    float4 a0 = {0, 0, 0, 0}, a1 = {0, 0, 0, 0}, a2 = {0, 0, 0, 0}, a3 = {0, 0, 0, 0};
    for (int kidx = 0; kidx < KN; ++kidx) {
        const float w = sc[kidx][qy];
        const int kx = kxmin + (kidx >> 5);
        const int kn = (kx << 5) | (kidx & 31);
        const float4* vp = (const float4*)(vT + ((size_t)bt * NN + kn) * CC + c0);
        float4 v0 = vp[0], v1 = vp[1], v2 = vp[2], v3 = vp[3];
        a0.x += w * v0.x; a0.y += w * v0.y; a0.z += w * v0.z; a0.w += w * v0.w;
        a1.x += w * v1.x; a1.y += w * v1.y; a1.z += w * v1.z; a1.w += w * v1.w;
        a2.x += w * v2.x; a2.y += w * v2.y; a2.z += w * v2.z; a2.w += w * v2.w;
        a3.x += w * v3.x; a3.y += w * v3.y; a3.z += w * v3.z; a3.w += w * v3.w;
    }
    const int qn = (qx << 5) | qy;
    float* ob = attout + (size_t)bt * CC * NN + qn;
    float vals[16] = {a0.x, a0.y, a0.z, a0.w, a1.x, a1.y, a1.z, a1.w,
                      a2.x, a2.y, a2.z, a2.w, a3.x, a3.y, a3.z, a3.w};
#pragma unroll
    for (int j = 0; j < 16; ++j) ob[(size_t)(c0 + j) * NN] = vals[j] * inv;
}

// ---------- kernel 5: fused output conv ----------
__global__ __launch_bounds__(256) void k_fuse(
    const float* __restrict__ attout, const float* __restrict__ Wf,
    const float* __restrict__ bf, float* __restrict__ fused)
{
    __shared__ float xs[CC][NT];
    const int t = threadIdx.x;
    const int bt = blockIdx.y;
    const int n0 = blockIdx.x * NT;
    const size_t base = (size_t)bt * CC * NN + n0;
    {
        int r = t >> 4;
        const int c4 = (t & 15) * 4;
        for (int i = 0; i < 8; ++i, r += 16)
            *(float4*)&xs[r][c4] = *(const float4*)(attout + base + (size_t)r * NN + c4);
    }
    __syncthreads();
    const int oi = t >> 4, ni = t & 15;
    const int o0 = oi * 8, nn = ni * 4;
    float acc[8][4];
    gemm_pass(xs, Wf, bf, o0, nn, acc);
    store_on(fused + base, o0, nn, acc);
}

// ---------- kernel 6: LIF spike scan over T ----------
__global__ __launch_bounds__(256) void k_lif(const float* __restrict__ fused,
                                             float* __restrict__ out)
{
    const int id = blockIdx.x * 256 + threadIdx.x; // over (b, c*n)
    const int b = id >> 17;          // C*N = 131072
    const int rem = id & 131071;
    float mem = 0.f;
#pragma unroll
    for (int tt = 0; tt < 4; ++tt) {
        const size_t a = (size_t)(b * 4 + tt) * (CC * NN) + rem;
        mem = mem * 0.5f + fused[a];
        const float spk = (mem > 1.0f) ? 1.0f : 0.0f;
        out[a] = spk;
        mem = (1.0f - spk) * mem;
    }
}

extern "C" void kernel_launch(void* const* d_in, const int* in_sizes, int n_in,
                              void* d_out, int out_size, void* d_ws, size_t ws_size,
                              hipStream_t stream) {
    (void)in_sizes; (void)n_in; (void)out_size; (void)ws_size;
    const float* edge = (const float*)d_in[0];
    const float* dvs  = (const float*)d_in[1];
    const float* We = (const float*)d_in[2];
    const float* be = (const float*)d_in[3];
    const float* Wd = (const float*)d_in[4];
    const float* bd = (const float*)d_in[5];
    const float* Wq = (const float*)d_in[6];
    const float* bq = (const float*)d_in[7];
    const float* Wk = (const float*)d_in[8];
    const float* bk = (const float*)d_in[9];
    const float* Wv = (const float*)d_in[10];
    const float* bv = (const float*)d_in[11];
    const float* Wf = (const float*)d_in[12];
    const float* bf = (const float*)d_in[13];
    float* out = (float*)d_out;
    float* ws = (float*)d_ws;
    const size_t S = (size_t)BTOT * CC * NN;
    float* ef  = ws;
    float* df  = ws + S;
    float* q   = ws + 2 * S;
    float* kT  = ws + 3 * S;
    float* vT  = ws + 4 * S;
    float* l2e = ws + 5 * S;
    float* sim = l2e + BTOT * NN;
    float* dens = sim + BTOT * NN;
    float* attout = ef; // reuse (ef dead after k_qkv)
    float* fused  = df; // reuse (df dead after k_qkv)

    k_proj<<<dim3(NN / NT, BTOT), 256, 0, stream>>>(edge, dvs, We, be, Wd, bd, ef, df, l2e, sim);
    k_dens<<<BTOT, 256, 0, stream>>>(l2e, dens);
    k_qkv<<<dim3(NN / NT, BTOT), 256, 0, stream>>>(ef, df, sim, dens, Wq, bq, Wk, bk, Wv, bv, q, kT, vT);
    k_attn<<<dim3(32, BTOT), 256, 0, stream>>>(q, kT, vT, attout);
    k_fuse<<<dim3(NN / NT, BTOT), 256, 0, stream>>>(attout, Wf, bf, fused);
    k_lif<<<4096, 256, 0, stream>>>(fused, out);
}

// Round 2
// 181.216 us; speedup vs baseline: 2.1294x; 2.1294x over previous
//
#include <hip/hip_runtime.h>
#include <math.h>

#define CC 128   // channels
#define NN 1024  // H*W
#define NT 64    // n-tile per GEMM block
#define BTOT 32  // B*T

// ---------- helpers ----------
__device__ __forceinline__ void gemm_pass(const float (*xs)[NT],
                                          const float* __restrict__ W,
                                          const float* __restrict__ bias,
                                          int o0, int nn, float acc[8][4]) {
#pragma unroll
    for (int r = 0; r < 8; ++r) {
        float b = bias[o0 + r];
#pragma unroll
        for (int j = 0; j < 4; ++j) acc[r][j] = b;
    }
    for (int c = 0; c < CC; c += 4) {
        float4 x0 = *(const float4*)&xs[c + 0][nn];
        float4 x1 = *(const float4*)&xs[c + 1][nn];
        float4 x2 = *(const float4*)&xs[c + 2][nn];
        float4 x3 = *(const float4*)&xs[c + 3][nn];
#pragma unroll
        for (int r = 0; r < 8; ++r) {
            float4 w = *(const float4*)(W + (o0 + r) * CC + c);
            acc[r][0] += w.x * x0.x + w.y * x1.x + w.z * x2.x + w.w * x3.x;
            acc[r][1] += w.x * x0.y + w.y * x1.y + w.z * x2.y + w.w * x3.y;
            acc[r][2] += w.x * x0.z + w.y * x1.z + w.z * x2.z + w.w * x3.z;
            acc[r][3] += w.x * x0.w + w.y * x1.w + w.z * x2.w + w.w * x3.w;
        }
    }
}

__device__ __forceinline__ void store_on(float* dst, int o0, int nn, const float acc[8][4]) {
    // dst pre-offset to [bt][*][n0]; layout [o][n]
#pragma unroll
    for (int r = 0; r < 8; ++r) {
        float4 v;
        v.x = acc[r][0]; v.y = acc[r][1]; v.z = acc[r][2]; v.w = acc[r][3];
        *(float4*)(dst + (size_t)(o0 + r) * NN + nn) = v;
    }
}

__device__ __forceinline__ void store_tr(float* dst, int o0, int nn, const float acc[8][4]) {
    // dst pre-offset to (bt*NN + n0)*CC; layout [n][c]
#pragma unroll
    for (int j = 0; j < 4; ++j) {
        float4 lo, hi;
        lo.x = acc[0][j]; lo.y = acc[1][j]; lo.z = acc[2][j]; lo.w = acc[3][j];
        hi.x = acc[4][j]; hi.y = acc[5][j]; hi.z = acc[6][j]; hi.w = acc[7][j];
        *(float4*)(dst + (size_t)(nn + j) * CC + o0) = lo;
        *(float4*)(dst + (size_t)(nn + j) * CC + o0 + 4) = hi;
    }
}

// ---------- kernel 1: ef/df projection + cosine sim + L2 norm ----------
__global__ __launch_bounds__(256) void k_proj(
    const float* __restrict__ edge, const float* __restrict__ dvs,
    const float* __restrict__ We, const float* __restrict__ be,
    const float* __restrict__ Wd, const float* __restrict__ bd,
    float* __restrict__ ef, float* __restrict__ df,
    float* __restrict__ l2e, float* __restrict__ sim)
{
    __shared__ float xe[CC][NT];
    __shared__ float xd[CC][NT];
    __shared__ float st2e[16][NT];
    __shared__ float st2d[16][NT];
    __shared__ float sted[16][NT];
    const int t = threadIdx.x;
    const int bt = blockIdx.y;
    const int n0 = blockIdx.x * NT;
    const size_t base = (size_t)bt * CC * NN + n0;
    {
        int r = t >> 4;
        const int c4 = (t & 15) * 4;
        for (int i = 0; i < 8; ++i, r += 16) {
            *(float4*)&xe[r][c4] = *(const float4*)(edge + base + (size_t)r * NN + c4);
            *(float4*)&xd[r][c4] = *(const float4*)(dvs + base + (size_t)r * NN + c4);
        }
    }
    __syncthreads();
    const int oi = t >> 4, ni = t & 15;
    const int o0 = oi * 8, nn = ni * 4;
    float accE[8][4], accD[8][4];
    gemm_pass(xe, We, be, o0, nn, accE);
    gemm_pass(xd, Wd, bd, o0, nn, accD);
    store_on(ef + base, o0, nn, accE);
    store_on(df + base, o0, nn, accD);
    // per-position stats over channels
    float p2e[4] = {0, 0, 0, 0}, p2d[4] = {0, 0, 0, 0}, ped[4] = {0, 0, 0, 0};
#pragma unroll
    for (int r = 0; r < 8; ++r)
#pragma unroll
        for (int j = 0; j < 4; ++j) {
            p2e[j] += accE[r][j] * accE[r][j];
            p2d[j] += accD[r][j] * accD[r][j];
            ped[j] += accE[r][j] * accD[r][j];
        }
#pragma unroll
    for (int j = 0; j < 4; ++j) {
        st2e[oi][nn + j] = p2e[j];
        st2d[oi][nn + j] = p2d[j];
        sted[oi][nn + j] = ped[j];
    }
    __syncthreads();
    if (t < NT) {
        float s2e = 0.f, s2d = 0.f, sed = 0.f;
#pragma unroll
        for (int i = 0; i < 16; ++i) {
            s2e += st2e[i][t];
            s2d += st2d[i][t];
            sed += sted[i][t];
        }
        float le = sqrtf(s2e), ld = sqrtf(s2d);
        float sm = (sed / ((le + 1e-6f) * (ld + 1e-6f)) + 1.0f) * 0.5f;
        l2e[(size_t)bt * NN + n0 + t] = le;
        sim[(size_t)bt * NN + n0 + t] = sm;
    }
}

// ---------- kernel 2: spatial softmax of l2e -> density ----------
__global__ __launch_bounds__(256) void k_dens(const float* __restrict__ l2e,
                                              float* __restrict__ dens)
{
    __shared__ float red1[4];
    __shared__ float red2[4];
    const int bt = blockIdx.x, t = threadIdx.x;
    const int lane = t & 63, wid = t >> 6;
    const float* x = l2e + (size_t)bt * NN;
    float v[4], m = -1e30f;
#pragma unroll
    for (int i = 0; i < 4; ++i) { v[i] = x[t + 256 * i]; m = fmaxf(m, v[i]); }
#pragma unroll
    for (int off = 32; off >= 1; off >>= 1) m = fmaxf(m, __shfl_xor(m, off));
    if (lane == 0) red1[wid] = m;
    __syncthreads();
    m = fmaxf(fmaxf(red1[0], red1[1]), fmaxf(red1[2], red1[3]));
    float e[4], s = 0.f;
#pragma unroll
    for (int i = 0; i < 4; ++i) { e[i] = expf(v[i] - m); s += e[i]; }
#pragma unroll
    for (int off = 32; off >= 1; off >>= 1) s += __shfl_xor(s, off);
    if (lane == 0) red2[wid] = s;
    __syncthreads();
    s = red2[0] + red2[1] + red2[2] + red2[3];
    const float scale = 1024.0f / s;
#pragma unroll
    for (int i = 0; i < 4; ++i) dens[(size_t)bt * NN + t + 256 * i] = e[i] * scale;
}

// ---------- kernel 3: gated q/k/v projections (q,k,v all transposed [n][c]) ----------
__global__ __launch_bounds__(256) void k_qkv(
    const float* __restrict__ ef, const float* __restrict__ df,
    const float* __restrict__ sim, const float* __restrict__ dens,
    const float* __restrict__ Wq, const float* __restrict__ bq,
    const float* __restrict__ Wk, const float* __restrict__ bk,
    const float* __restrict__ Wv, const float* __restrict__ bv,
    float* __restrict__ qT, float* __restrict__ kT, float* __restrict__ vT)
{
    __shared__ float xq[CC][NT];
    __shared__ float xd2[CC][NT];
    const int t = threadIdx.x;
    const int bt = blockIdx.y;
    const int n0 = blockIdx.x * NT;
    const size_t base = (size_t)bt * CC * NN + n0;
    {
        int r = t >> 4;
        const int c4 = (t & 15) * 4;
        float4 sv = *(const float4*)(sim + (size_t)bt * NN + n0 + c4);
        float4 dv = *(const float4*)(dens + (size_t)bt * NN + n0 + c4);
        for (int i = 0; i < 8; ++i, r += 16) {
            float4 e4 = *(const float4*)(ef + base + (size_t)r * NN + c4);
            float4 d4 = *(const float4*)(df + base + (size_t)r * NN + c4);
            float4 a, b;
            a.x = e4.x * sv.x; a.y = e4.y * sv.y; a.z = e4.z * sv.z; a.w = e4.w * sv.w;
            b.x = d4.x * dv.x; b.y = d4.y * dv.y; b.z = d4.z * dv.z; b.w = d4.w * dv.w;
            *(float4*)&xq[r][c4] = a;
            *(float4*)&xd2[r][c4] = b;
        }
    }
    __syncthreads();
    const int oi = t >> 4, ni = t & 15;
    const int o0 = oi * 8, nn = ni * 4;
    float acc[8][4];
    gemm_pass(xq, Wq, bq, o0, nn, acc);
    store_tr(qT + ((size_t)bt * NN + n0) * CC, o0, nn, acc);
    gemm_pass(xd2, Wk, bk, o0, nn, acc);
    store_tr(kT + ((size_t)bt * NN + n0) * CC, o0, nn, acc);
    gemm_pass(xd2, Wv, bv, o0, nn, acc);
    store_tr(vT + ((size_t)bt * NN + n0) * CC, o0, nn, acc);
}

// ---------- kernel 4: windowed attention (7x7 band only) ----------
// LDS tiles hold 32 rows x 32 float4-slots; slot stored at (slot ^ row) so
// that lanes walking consecutive rows at a fixed logical slot hit distinct
// banks (any 8 consecutive rows have distinct low-3 bits -> conflict-free b128).
__device__ __forceinline__ void stage_tile(const float4* __restrict__ src,
                                           float4* dst, int t) {
#pragma unroll
    for (int j = 0; j < 4; ++j) {
        const int i = t + 256 * j;
        const int row = i >> 5, slot = i & 31;
        dst[(row << 5) | (slot ^ row)] = src[i];
    }
}

__global__ __launch_bounds__(256) void k_attn(
    const float* __restrict__ qT, const float* __restrict__ kT,
    const float* __restrict__ vT, float* __restrict__ attout)
{
    __shared__ float4 q_s[32 * 32];   // 16KB
    __shared__ float4 kv_s[32 * 32];  // 16KB (K tiles in pass A, V tiles in pass B)
    __shared__ float sc[49][33];      // scores / exp weights
    __shared__ float red[8][33];
    const int t = threadIdx.x;
    const int qx = blockIdx.x;
    const int bt = blockIdx.y;
    const int qy = t & 31, kg = t >> 5;
    const int kxmin = max(qx - 3, 0), kxmax = min(qx + 3, 31);
    const int NKX = kxmax - kxmin + 1;
    const int J = NKX * 7;

    stage_tile((const float4*)(qT + ((size_t)bt * NN + qx * 32) * CC), q_s, t);

    // ---- pass A: scores for the 7x7 window ----
    for (int kxi = 0; kxi < NKX; ++kxi) {
        const int kx = kxmin + kxi;
        __syncthreads();  // prior tile consumed (also covers q_s staging)
        stage_tile((const float4*)(kT + ((size_t)bt * NN + kx * 32) * CC), kv_s, t);
        __syncthreads();
        if (kg < 7) {
            const int ky = qy + kg - 3;
            const int kyc = min(max(ky, 0), 31);
            const int qb = qy << 5, kb = kyc << 5;
            float acc = 0.f;
#pragma unroll
            for (int s = 0; s < 32; ++s) {
                float4 qv = q_s[qb | (s ^ qy)];
                float4 kv = kv_s[kb | (s ^ kyc)];
                acc += qv.x * kv.x + qv.y * kv.y + qv.z * kv.z + qv.w * kv.w;
            }
            sc[kxi * 7 + kg][qy] =
                (ky == kyc) ? acc * 0.08838834764831843f : -1e30f;
        }
    }
    __syncthreads();

    // ---- softmax over the J window scores of each query ----
    float m = -1e30f;
    for (int j = kg; j < J; j += 8) m = fmaxf(m, sc[j][qy]);
    red[kg][qy] = m;
    __syncthreads();
    m = red[0][qy];
#pragma unroll
    for (int i = 1; i < 8; ++i) m = fmaxf(m, red[i][qy]);
    __syncthreads();  // before reusing red
    float ps = 0.f;
    for (int j = kg; j < J; j += 8) {
        float e = expf(sc[j][qy] - m);
        sc[j][qy] = e;
        ps += e;
    }
    red[kg][qy] = ps;
    __syncthreads();
    float S = 0.f;
#pragma unroll
    for (int i = 0; i < 8; ++i) S += red[i][qy];
    const float inv = 1.0f / S;

    // ---- pass B: PV accumulate; thread owns (qy, 16 channels) ----
    const int cg = kg;
    float4 a0 = {0, 0, 0, 0}, a1 = {0, 0, 0, 0}, a2 = {0, 0, 0, 0}, a3 = {0, 0, 0, 0};
    for (int kxi = 0; kxi < NKX; ++kxi) {
        const int kx = kxmin + kxi;
        __syncthreads();
        stage_tile((const float4*)(vT + ((size_t)bt * NN + kx * 32) * CC), kv_s, t);
        __syncthreads();
#pragma unroll
        for (int dy = 0; dy < 7; ++dy) {
            const int ky = qy + dy - 3;
            const int kyc = min(max(ky, 0), 31);
            const float w = sc[kxi * 7 + dy][qy];  // exactly 0.0 for OOB ky
            const int rb = kyc << 5;
            float4 v0 = kv_s[rb | ((4 * cg + 0) ^ kyc)];
            float4 v1 = kv_s[rb | ((4 * cg + 1) ^ kyc)];
            float4 v2 = kv_s[rb | ((4 * cg + 2) ^ kyc)];
            float4 v3 = kv_s[rb | ((4 * cg + 3) ^ kyc)];
            a0.x += w * v0.x; a0.y += w * v0.y; a0.z += w * v0.z; a0.w += w * v0.w;
            a1.x += w * v1.x; a1.y += w * v1.y; a1.z += w * v1.z; a1.w += w * v1.w;
            a2.x += w * v2.x; a2.y += w * v2.y; a2.z += w * v2.z; a2.w += w * v2.w;
            a3.x += w * v3.x; a3.y += w * v3.y; a3.z += w * v3.z; a3.w += w * v3.w;
        }
    }
    const int qn = (qx << 5) | qy;
    float* ob = attout + (size_t)bt * CC * NN + (size_t)cg * 16 * NN + qn;
    float vals[16] = {a0.x, a0.y, a0.z, a0.w, a1.x, a1.y, a1.z, a1.w,
                      a2.x, a2.y, a2.z, a2.w, a3.x, a3.y, a3.z, a3.w};
#pragma unroll
    for (int j = 0; j < 16; ++j) ob[(size_t)j * NN] = vals[j] * inv;
}

// ---------- kernel 5: fused output conv ----------
__global__ __launch_bounds__(256) void k_fuse(
    const float* __restrict__ attout, const float* __restrict__ Wf,
    const float* __restrict__ bf, float* __restrict__ fused)
{
    __shared__ float xs[CC][NT];
    const int t = threadIdx.x;
    const int bt = blockIdx.y;
    const int n0 = blockIdx.x * NT;
    const size_t base = (size_t)bt * CC * NN + n0;
    {
        int r = t >> 4;
        const int c4 = (t & 15) * 4;
        for (int i = 0; i < 8; ++i, r += 16)
            *(float4*)&xs[r][c4] = *(const float4*)(attout + base + (size_t)r * NN + c4);
    }
    __syncthreads();
    const int oi = t >> 4, ni = t & 15;
    const int o0 = oi * 8, nn = ni * 4;
    float acc[8][4];
    gemm_pass(xs, Wf, bf, o0, nn, acc);
    store_on(fused + base, o0, nn, acc);
}

// ---------- kernel 6: LIF spike scan over T ----------
__global__ __launch_bounds__(256) void k_lif(const float* __restrict__ fused,
                                             float* __restrict__ out)
{
    const int id = blockIdx.x * 256 + threadIdx.x; // over (b, c*n)
    const int b = id >> 17;          // C*N = 131072
    const int rem = id & 131071;
    float mem = 0.f;
#pragma unroll
    for (int tt = 0; tt < 4; ++tt) {
        const size_t a = (size_t)(b * 4 + tt) * (CC * NN) + rem;
        mem = mem * 0.5f + fused[a];
        const float spk = (mem > 1.0f) ? 1.0f : 0.0f;
        out[a] = spk;
        mem = (1.0f - spk) * mem;
    }
}

extern "C" void kernel_launch(void* const* d_in, const int* in_sizes, int n_in,
                              void* d_out, int out_size, void* d_ws, size_t ws_size,
                              hipStream_t stream) {
    (void)in_sizes; (void)n_in; (void)out_size; (void)ws_size;
    const float* edge = (const float*)d_in[0];
    const float* dvs  = (const float*)d_in[1];
    const float* We = (const float*)d_in[2];
    const float* be = (const float*)d_in[3];
    const float* Wd = (const float*)d_in[4];
    const float* bd = (const float*)d_in[5];
    const float* Wq = (const float*)d_in[6];
    const float* bq = (const float*)d_in[7];
    const float* Wk = (const float*)d_in[8];
    const float* bk = (const float*)d_in[9];
    const float* Wv = (const float*)d_in[10];
    const float* bv = (const float*)d_in[11];
    const float* Wf = (const float*)d_in[12];
    const float* bf = (const float*)d_in[13];
    float* out = (float*)d_out;
    float* ws = (float*)d_ws;
    const size_t S = (size_t)BTOT * CC * NN;
    float* ef  = ws;
    float* df  = ws + S;
    float* qT  = ws + 2 * S;
    float* kT  = ws + 3 * S;
    float* vT  = ws + 4 * S;
    float* l2e = ws + 5 * S;
    float* sim = l2e + BTOT * NN;
    float* dens = sim + BTOT * NN;
    float* attout = ef; // reuse (ef dead after k_qkv)
    float* fused  = df; // reuse (df dead after k_qkv)

    k_proj<<<dim3(NN / NT, BTOT), 256, 0, stream>>>(edge, dvs, We, be, Wd, bd, ef, df, l2e, sim);
    k_dens<<<BTOT, 256, 0, stream>>>(l2e, dens);
    k_qkv<<<dim3(NN / NT, BTOT), 256, 0, stream>>>(ef, df, sim, dens, Wq, bq, Wk, bk, Wv, bv, qT, kT, vT);
    k_attn<<<dim3(32, BTOT), 256, 0, stream>>>(qT, kT, vT, attout);
    k_fuse<<<dim3(NN / NT, BTOT), 256, 0, stream>>>(attout, Wf, bf, fused);
    k_lif<<<4096, 256, 0, stream>>>(fused, out);
}

// Round 3
// 112.938 us; speedup vs baseline: 3.4167x; 1.6046x over previous
//
#include <hip/hip_runtime.h>
#include <math.h>

#define CC 128   // channels
#define NN 1024  // H*W
#define BTOT 32  // B*T
#define CP 136   // LDS row stride in bf16 elems (272B = 17*16 -> b128-aligned rows)

typedef unsigned short u16;
typedef u16 u16x8 __attribute__((ext_vector_type(8)));
typedef u16 u16x4 __attribute__((ext_vector_type(4)));
typedef __bf16 bf16x8 __attribute__((ext_vector_type(8)));
typedef float f32x4 __attribute__((ext_vector_type(4)));

__device__ __forceinline__ u16 f2b(float f) {
    unsigned int u = __float_as_uint(f);
    u += 0x7FFFu + ((u >> 16) & 1u);   // RNE
    return (u16)(u >> 16);
}
__device__ __forceinline__ float b2f(u16 u) {
    return __uint_as_float(((unsigned int)u) << 16);
}

// ---------- MFMA helpers ----------
// A-frag (weights): lane l holds W[16*ot + (l&15)][32*kk + 8*(l>>4) + j], j=0..7,
// pre-packed by k_wcvt at WB[((ot*4+kk)*64 + l)*8].
// B-frag (acts): lane l holds x[n0 + (l&15)][32*kk + 8*(l>>4) + j] from LDS [n][c].
__device__ __forceinline__ void loadB(const u16* brow, int g, bf16x8 bfr[4]) {
#pragma unroll
    for (int kk = 0; kk < 4; ++kk)
        bfr[kk] = *(const bf16x8*)(brow + kk * 32 + g * 8);
}
__device__ __forceinline__ void mm128(const bf16x8 bfr[4], const u16* __restrict__ WB,
                                      int l, f32x4 acc[8]) {
#pragma unroll
    for (int ot = 0; ot < 8; ++ot) {
        f32x4 a = {0.f, 0.f, 0.f, 0.f};
#pragma unroll
        for (int kk = 0; kk < 4; ++kk) {
            bf16x8 afr = *(const bf16x8*)(WB + ((size_t)(ot * 4 + kk) * 64 + l) * 8);
            a = __builtin_amdgcn_mfma_f32_16x16x32_bf16(afr, bfr[kk], a, 0, 0, 0);
        }
        acc[ot] = a;
    }
}

// ---------- kernel 0: pack 6 weight matrices into bf16 frag order ----------
__global__ __launch_bounds__(256) void k_wcvt(
    const float* __restrict__ W0, const float* __restrict__ W1,
    const float* __restrict__ W2, const float* __restrict__ W3,
    const float* __restrict__ W4, const float* __restrict__ W5,
    u16* __restrict__ out)
{
    const int gid = blockIdx.x * 256 + threadIdx.x;  // 6*2048
    const int wi = gid >> 11, rem = gid & 2047;
    const float* W = (wi == 0) ? W0 : (wi == 1) ? W1 : (wi == 2) ? W2
                   : (wi == 3) ? W3 : (wi == 4) ? W4 : W5;
    const int ot = rem >> 8, kk = (rem >> 6) & 3, l = rem & 63;
    const int row = ot * 16 + (l & 15), col = kk * 32 + (l >> 4) * 8;
    float4 a = *(const float4*)(W + row * CC + col);
    float4 b = *(const float4*)(W + row * CC + col + 4);
    u16x8 u;
    u[0] = f2b(a.x); u[1] = f2b(a.y); u[2] = f2b(a.z); u[3] = f2b(a.w);
    u[4] = f2b(b.x); u[5] = f2b(b.y); u[6] = f2b(b.z); u[7] = f2b(b.w);
    *(u16x8*)(out + (size_t)wi * 16384 + ((size_t)(ot * 4 + kk) * 64 + l) * 8) = u;
}

// ---------- kernel 1: front (ef/df/stats/qkv), 5 chained MFMA GEMMs ----------
__global__ __launch_bounds__(256) void k_front(
    const float* __restrict__ edge, const float* __restrict__ dvs,
    const u16* __restrict__ WeB, const u16* __restrict__ WdB,
    const u16* __restrict__ WqB, const u16* __restrict__ WkB,
    const u16* __restrict__ WvB,
    const float* __restrict__ be, const float* __restrict__ bd,
    const float* __restrict__ bq,
    float* __restrict__ l2e_out,
    u16* __restrict__ qT, u16* __restrict__ kT, u16* __restrict__ vT)
{
    __shared__ u16 bufA[64 * CP];
    __shared__ u16 bufB[64 * CP];
    const int t = threadIdx.x;
    const int bt = blockIdx.y;
    const int n0b = blockIdx.x * 64;
    const float* eb = edge + (size_t)bt * CC * NN + n0b;
    const float* db = dvs + (size_t)bt * CC * NN + n0b;

    // P1: transpose-stage [c][n] fp32 -> [n][c] bf16
#pragma unroll
    for (int j = 0; j < 2; ++j) {
        const int i = t + 256 * j;
        const int c4 = i >> 4, p = i & 15;  // c-block, n-block
        float4 e[4], d[4];
#pragma unroll
        for (int m = 0; m < 4; ++m) {
            e[m] = *(const float4*)(eb + (size_t)(4 * c4 + m) * NN + 4 * p);
            d[m] = *(const float4*)(db + (size_t)(4 * c4 + m) * NN + 4 * p);
        }
#pragma unroll
        for (int n = 0; n < 4; ++n) {
            const float* ef_ = (const float*)&e[0];
            u16x4 ue, ud;
            ue[0] = f2b(((const float*)&e[0])[n]); ud[0] = f2b(((const float*)&d[0])[n]);
            ue[1] = f2b(((const float*)&e[1])[n]); ud[1] = f2b(((const float*)&d[1])[n]);
            ue[2] = f2b(((const float*)&e[2])[n]); ud[2] = f2b(((const float*)&d[2])[n]);
            ue[3] = f2b(((const float*)&e[3])[n]); ud[3] = f2b(((const float*)&d[3])[n]);
            (void)ef_;
            *(u16x4*)&bufA[(4 * p + n) * CP + 4 * c4] = ue;
            *(u16x4*)&bufB[(4 * p + n) * CP + 4 * c4] = ud;
        }
    }
    __syncthreads();  // the only block-wide barrier

    const int l = t & 63, w = t >> 6;
    const int l15 = l & 15, g = l >> 4;
    const int nloc = w * 16 + l15;                 // this lane's LDS row
    const size_t gn = (size_t)bt * NN + n0b + nloc; // global n index
    u16* browA = bufA + nloc * CP;
    u16* browB = bufB + nloc * CP;

    f32x4 acc[8];
    bf16x8 bfr[4];

    // --- ef = We*edge + be ; write back to bufA (bf16) ---
    loadB(browA, g, bfr);
    mm128(bfr, WeB, l, acc);
#pragma unroll
    for (int ot = 0; ot < 8; ++ot) {
        f32x4 b4 = *(const f32x4*)(be + 16 * ot + 4 * g);
        u16x4 u;
#pragma unroll
        for (int r = 0; r < 4; ++r) u[r] = f2b(acc[ot][r] + b4[r]);
        *(u16x4*)&browA[16 * ot + 4 * g] = u;
    }
    // --- df = Wd*dvs + bd ; write back to bufB ---
    loadB(browB, g, bfr);
    mm128(bfr, WdB, l, acc);
#pragma unroll
    for (int ot = 0; ot < 8; ++ot) {
        f32x4 b4 = *(const f32x4*)(bd + 16 * ot + 4 * g);
        u16x4 u;
#pragma unroll
        for (int r = 0; r < 4; ++r) u[r] = f2b(acc[ot][r] + b4[r]);
        *(u16x4*)&browB[16 * ot + 4 * g] = u;
    }
    // --- stats over channels for this lane's n ---
    float s2e = 0.f, s2d = 0.f, sed = 0.f;
#pragma unroll
    for (int m = 0; m < 4; ++m) {
        u16x8 ue = *(const u16x8*)(browA + g * 32 + m * 8);
        u16x8 ud = *(const u16x8*)(browB + g * 32 + m * 8);
#pragma unroll
        for (int jj = 0; jj < 8; ++jj) {
            float fe = b2f(ue[jj]), fd = b2f(ud[jj]);
            s2e += fe * fe; s2d += fd * fd; sed += fe * fd;
        }
    }
    s2e += __shfl_xor(s2e, 16); s2e += __shfl_xor(s2e, 32);
    s2d += __shfl_xor(s2d, 16); s2d += __shfl_xor(s2d, 32);
    sed += __shfl_xor(sed, 16); sed += __shfl_xor(sed, 32);
    const float le = sqrtf(s2e), ld = sqrtf(s2d);
    const float sim = (sed / ((le + 1e-6f) * (ld + 1e-6f)) + 1.0f) * 0.5f;
    if (g == 0) l2e_out[gn] = le;

    // --- q = sim*(Wq*ef) + bq ---
    loadB(browA, g, bfr);
    mm128(bfr, WqB, l, acc);
#pragma unroll
    for (int ot = 0; ot < 8; ++ot) {
        f32x4 b4 = *(const f32x4*)(bq + 16 * ot + 4 * g);
        u16x4 u;
#pragma unroll
        for (int r = 0; r < 4; ++r) u[r] = f2b(sim * acc[ot][r] + b4[r]);
        *(u16x4*)(qT + gn * CC + 16 * ot + 4 * g) = u;
    }
    // --- kraw = Wk*df (dens & bias applied in k_attn) ---
    loadB(browB, g, bfr);
    mm128(bfr, WkB, l, acc);
#pragma unroll
    for (int ot = 0; ot < 8; ++ot) {
        u16x4 u;
#pragma unroll
        for (int r = 0; r < 4; ++r) u[r] = f2b(acc[ot][r]);
        *(u16x4*)(kT + gn * CC + 16 * ot + 4 * g) = u;
    }
    // --- vraw = Wv*df ---
    mm128(bfr, WvB, l, acc);
#pragma unroll
    for (int ot = 0; ot < 8; ++ot) {
        u16x4 u;
#pragma unroll
        for (int r = 0; r < 4; ++r) u[r] = f2b(acc[ot][r]);
        *(u16x4*)(vT + gn * CC + 16 * ot + 4 * g) = u;
    }
}

// ---------- kernel 2: spatial softmax of l2e -> density ----------
__global__ __launch_bounds__(256) void k_dens(const float* __restrict__ l2e,
                                              float* __restrict__ dens)
{
    __shared__ float red1[4];
    __shared__ float red2[4];
    const int bt = blockIdx.x, t = threadIdx.x;
    const int lane = t & 63, wid = t >> 6;
    const float* x = l2e + (size_t)bt * NN;
    float v[4], m = -1e30f;
#pragma unroll
    for (int i = 0; i < 4; ++i) { v[i] = x[t + 256 * i]; m = fmaxf(m, v[i]); }
#pragma unroll
    for (int off = 32; off >= 1; off >>= 1) m = fmaxf(m, __shfl_xor(m, off));
    if (lane == 0) red1[wid] = m;
    __syncthreads();
    m = fmaxf(fmaxf(red1[0], red1[1]), fmaxf(red1[2], red1[3]));
    float e[4], s = 0.f;
#pragma unroll
    for (int i = 0; i < 4; ++i) { e[i] = expf(v[i] - m); s += e[i]; }
#pragma unroll
    for (int off = 32; off >= 1; off >>= 1) s += __shfl_xor(s, off);
    if (lane == 0) red2[wid] = s;
    __syncthreads();
    s = red2[0] + red2[1] + red2[2] + red2[3];
    const float scale = 1024.0f / s;
#pragma unroll
    for (int i = 0; i < 4; ++i) dens[(size_t)bt * NN + t + 256 * i] = e[i] * scale;
}

// ---------- kernel 3: windowed attention (bf16 in/out) ----------
__global__ __launch_bounds__(256) void k_attn(
    const u16* __restrict__ qT, const u16* __restrict__ kT,
    const u16* __restrict__ vT, const float* __restrict__ dens,
    const float* __restrict__ bk, const float* __restrict__ bv,
    u16* __restrict__ attT)
{
    __shared__ float4 q_s[32 * 32];
    __shared__ float4 kv_s[32 * 32];
    __shared__ float sc[49][33];
    __shared__ float red[8][33];
    const int t = threadIdx.x;
    const int qx = blockIdx.x;
    const int bt = blockIdx.y;
    const int qy = t & 31, kg = t >> 5;
    const int kxmin = max(qx - 3, 0), kxmax = min(qx + 3, 31);
    const int NKX = kxmax - kxmin + 1;
    const int J = NKX * 7;

    // stage q (already final: sim*qraw + bq applied upstream)
#pragma unroll
    for (int j = 0; j < 2; ++j) {
        const int i = t + 256 * j;
        const int row = i >> 4, s8 = i & 15;
        u16x8 u = *(const u16x8*)(qT + ((size_t)bt * NN + qx * 32 + row) * CC + 8 * s8);
        float4 lo, hi;
        lo.x = b2f(u[0]); lo.y = b2f(u[1]); lo.z = b2f(u[2]); lo.w = b2f(u[3]);
        hi.x = b2f(u[4]); hi.y = b2f(u[5]); hi.z = b2f(u[6]); hi.w = b2f(u[7]);
        q_s[(row << 5) | ((2 * s8) ^ row)] = lo;
        q_s[(row << 5) | ((2 * s8 + 1) ^ row)] = hi;
    }

    // ---- pass A: scores (k = dens*kraw + bk applied on stage) ----
    for (int kxi = 0; kxi < NKX; ++kxi) {
        const int kx = kxmin + kxi;
        __syncthreads();
        {
            const u16* gb = kT + ((size_t)bt * NN + kx * 32) * CC;
            const float* dr = dens + (size_t)bt * NN + kx * 32;
#pragma unroll
            for (int j = 0; j < 2; ++j) {
                const int i = t + 256 * j;
                const int row = i >> 4, s8 = i & 15;
                u16x8 u = *(const u16x8*)(gb + (size_t)row * CC + 8 * s8);
                const float dn = dr[row];
                f32x4 b0 = *(const f32x4*)(bk + 8 * s8);
                f32x4 b1 = *(const f32x4*)(bk + 8 * s8 + 4);
                float4 lo, hi;
                lo.x = dn * b2f(u[0]) + b0[0]; lo.y = dn * b2f(u[1]) + b0[1];
                lo.z = dn * b2f(u[2]) + b0[2]; lo.w = dn * b2f(u[3]) + b0[3];
                hi.x = dn * b2f(u[4]) + b1[0]; hi.y = dn * b2f(u[5]) + b1[1];
                hi.z = dn * b2f(u[6]) + b1[2]; hi.w = dn * b2f(u[7]) + b1[3];
                kv_s[(row << 5) | ((2 * s8) ^ row)] = lo;
                kv_s[(row << 5) | ((2 * s8 + 1) ^ row)] = hi;
            }
        }
        __syncthreads();
        if (kg < 7) {
            const int ky = qy + kg - 3;
            const int kyc = min(max(ky, 0), 31);
            const int qb = qy << 5, kb = kyc << 5;
            float acc = 0.f;
#pragma unroll
            for (int s = 0; s < 32; ++s) {
                float4 qv = q_s[qb | (s ^ qy)];
                float4 kv = kv_s[kb | (s ^ kyc)];
                acc += qv.x * kv.x + qv.y * kv.y + qv.z * kv.z + qv.w * kv.w;
            }
            sc[kxi * 7 + kg][qy] =
                (ky == kyc) ? acc * 0.08838834764831843f : -1e30f;
        }
    }
    __syncthreads();

    // ---- softmax ----
    float m = -1e30f;
    for (int j = kg; j < J; j += 8) m = fmaxf(m, sc[j][qy]);
    red[kg][qy] = m;
    __syncthreads();
    m = red[0][qy];
#pragma unroll
    for (int i = 1; i < 8; ++i) m = fmaxf(m, red[i][qy]);
    __syncthreads();
    float ps = 0.f;
    for (int j = kg; j < J; j += 8) {
        float e = expf(sc[j][qy] - m);
        sc[j][qy] = e;
        ps += e;
    }
    red[kg][qy] = ps;
    __syncthreads();
    float S = 0.f;
#pragma unroll
    for (int i = 0; i < 8; ++i) S += red[i][qy];
    const float inv = 1.0f / S;

    // ---- pass B: PV (v = dens*vraw + bv on stage) ----
    const int cg = kg;
    float4 a0 = {0, 0, 0, 0}, a1 = {0, 0, 0, 0}, a2 = {0, 0, 0, 0}, a3 = {0, 0, 0, 0};
    for (int kxi = 0; kxi < NKX; ++kxi) {
        const int kx = kxmin + kxi;
        __syncthreads();
        {
            const u16* gb = vT + ((size_t)bt * NN + kx * 32) * CC;
            const float* dr = dens + (size_t)bt * NN + kx * 32;
#pragma unroll
            for (int j = 0; j < 2; ++j) {
                const int i = t + 256 * j;
                const int row = i >> 4, s8 = i & 15;
                u16x8 u = *(const u16x8*)(gb + (size_t)row * CC + 8 * s8);
                const float dn = dr[row];
                f32x4 b0 = *(const f32x4*)(bv + 8 * s8);
                f32x4 b1 = *(const f32x4*)(bv + 8 * s8 + 4);
                float4 lo, hi;
                lo.x = dn * b2f(u[0]) + b0[0]; lo.y = dn * b2f(u[1]) + b0[1];
                lo.z = dn * b2f(u[2]) + b0[2]; lo.w = dn * b2f(u[3]) + b0[3];
                hi.x = dn * b2f(u[4]) + b1[0]; hi.y = dn * b2f(u[5]) + b1[1];
                hi.z = dn * b2f(u[6]) + b1[2]; hi.w = dn * b2f(u[7]) + b1[3];
                kv_s[(row << 5) | ((2 * s8) ^ row)] = lo;
                kv_s[(row << 5) | ((2 * s8 + 1) ^ row)] = hi;
            }
        }
        __syncthreads();
#pragma unroll
        for (int dy = 0; dy < 7; ++dy) {
            const int ky = qy + dy - 3;
            const int kyc = min(max(ky, 0), 31);
            const float wgt = sc[kxi * 7 + dy][qy];  // exactly 0 for OOB
            const int rb = kyc << 5;
            float4 v0 = kv_s[rb | ((4 * cg + 0) ^ kyc)];
            float4 v1 = kv_s[rb | ((4 * cg + 1) ^ kyc)];
            float4 v2 = kv_s[rb | ((4 * cg + 2) ^ kyc)];
            float4 v3 = kv_s[rb | ((4 * cg + 3) ^ kyc)];
            a0.x += wgt * v0.x; a0.y += wgt * v0.y; a0.z += wgt * v0.z; a0.w += wgt * v0.w;
            a1.x += wgt * v1.x; a1.y += wgt * v1.y; a1.z += wgt * v1.z; a1.w += wgt * v1.w;
            a2.x += wgt * v2.x; a2.y += wgt * v2.y; a2.z += wgt * v2.z; a2.w += wgt * v2.w;
            a3.x += wgt * v3.x; a3.y += wgt * v3.y; a3.z += wgt * v3.z; a3.w += wgt * v3.w;
        }
    }
    const int qn = qx * 32 + qy;
    u16* ob = attT + ((size_t)bt * NN + qn) * CC + cg * 16;
    float vals[16] = {a0.x, a0.y, a0.z, a0.w, a1.x, a1.y, a1.z, a1.w,
                      a2.x, a2.y, a2.z, a2.w, a3.x, a3.y, a3.z, a3.w};
    u16x8 o0, o1;
#pragma unroll
    for (int j = 0; j < 8; ++j) { o0[j] = f2b(vals[j] * inv); o1[j] = f2b(vals[8 + j] * inv); }
    *(u16x8*)ob = o0;
    *(u16x8*)(ob + 8) = o1;
}

// ---------- kernel 4: fused output conv + LIF scan ----------
__global__ __launch_bounds__(128) void k_flif(
    const u16* __restrict__ attT, const u16* __restrict__ WfB,
    const float* __restrict__ bf, float* __restrict__ out)
{
    __shared__ u16 bufC[32 * CP];
    __shared__ float spk[128 * 36];
    const int t = threadIdx.x;
    const int n0b = blockIdx.x * 32;
    const int b = blockIdx.y;
    const int l = t & 63, w = t >> 6;
    const int l15 = l & 15, g = l >> 4;
    const int nloc = w * 16 + l15;
    f32x4 mem[8];
#pragma unroll
    for (int ot = 0; ot < 8; ++ot) mem[ot] = (f32x4){0.f, 0.f, 0.f, 0.f};

    for (int tt = 0; tt < 4; ++tt) {
        // stage att tile (straight bf16 copy)
#pragma unroll
        for (int j = 0; j < 4; ++j) {
            const int i = t + 128 * j;
            const int row = i >> 4, s8 = i & 15;
            *(u16x8*)&bufC[row * CP + 8 * s8] =
                *(const u16x8*)(attT + ((size_t)(b * 4 + tt) * NN + n0b + row) * CC + 8 * s8);
        }
        __syncthreads();
        bf16x8 bfr[4];
        loadB(bufC + nloc * CP, g, bfr);
#pragma unroll
        for (int ot = 0; ot < 8; ++ot) {
            f32x4 a = *(const f32x4*)(bf + 16 * ot + 4 * g);  // bias init
#pragma unroll
            for (int kk = 0; kk < 4; ++kk) {
                bf16x8 afr = *(const bf16x8*)(WfB + ((size_t)(ot * 4 + kk) * 64 + l) * 8);
                a = __builtin_amdgcn_mfma_f32_16x16x32_bf16(afr, bfr[kk], a, 0, 0, 0);
            }
            // LIF
            f32x4 mv = mem[ot] * 0.5f + a;
#pragma unroll
            for (int r = 0; r < 4; ++r) {
                const float s = (mv[r] > 1.0f) ? 1.0f : 0.0f;
                spk[(16 * ot + 4 * g + r) * 36 + nloc] = s;
                if (mv[r] > 1.0f) mv[r] = 0.f;
            }
            mem[ot] = mv;
        }
        __syncthreads();
        // coalesced spike store
#pragma unroll
        for (int j = 0; j < 8; ++j) {
            const int i = t + 128 * j;
            const int row = i >> 3, n4 = (i & 7) * 4;
            *(float4*)(out + ((size_t)(b * 4 + tt) * CC + row) * NN + n0b + n4) =
                *(const float4*)&spk[row * 36 + n4];
        }
    }
}

extern "C" void kernel_launch(void* const* d_in, const int* in_sizes, int n_in,
                              void* d_out, int out_size, void* d_ws, size_t ws_size,
                              hipStream_t stream) {
    (void)in_sizes; (void)n_in; (void)out_size; (void)ws_size;
    const float* edge = (const float*)d_in[0];
    const float* dvs  = (const float*)d_in[1];
    const float* We = (const float*)d_in[2];
    const float* be = (const float*)d_in[3];
    const float* Wd = (const float*)d_in[4];
    const float* bd = (const float*)d_in[5];
    const float* Wq = (const float*)d_in[6];
    const float* bq = (const float*)d_in[7];
    const float* Wk = (const float*)d_in[8];
    const float* bk = (const float*)d_in[9];
    const float* Wv = (const float*)d_in[10];
    const float* bv = (const float*)d_in[11];
    const float* Wf = (const float*)d_in[12];
    const float* bf = (const float*)d_in[13];
    float* out = (float*)d_out;

    const size_t S = (size_t)BTOT * NN * CC;  // 4.19M elems
    u16* qT   = (u16*)d_ws;
    u16* kT   = qT + S;
    u16* vT   = kT + S;
    u16* attT = vT + S;
    u16* WbAll = attT + S;                    // 6 * 16384 u16
    float* l2e  = (float*)(WbAll + 6 * 16384);
    float* dens = l2e + BTOT * NN;
    u16* WeB = WbAll + 0 * 16384;
    u16* WdB = WbAll + 1 * 16384;
    u16* WqB = WbAll + 2 * 16384;
    u16* WkB = WbAll + 3 * 16384;
    u16* WvB = WbAll + 4 * 16384;
    u16* WfB = WbAll + 5 * 16384;

    k_wcvt<<<48, 256, 0, stream>>>(We, Wd, Wq, Wk, Wv, Wf, WbAll);
    k_front<<<dim3(16, BTOT), 256, 0, stream>>>(edge, dvs, WeB, WdB, WqB, WkB, WvB,
                                                be, bd, bq, l2e, qT, kT, vT);
    k_dens<<<BTOT, 256, 0, stream>>>(l2e, dens);
    k_attn<<<dim3(32, BTOT), 256, 0, stream>>>(qT, kT, vT, dens, bk, bv, attT);
    k_flif<<<dim3(32, 8), 128, 0, stream>>>(attT, WfB, bf, out);
}

// Round 4
// 89.663 us; speedup vs baseline: 4.3036x; 1.2596x over previous
//
#include <hip/hip_runtime.h>
#include <math.h>

#define CC 128   // channels
#define NN 1024  // H*W
#define BTOT 32  // B*T
#define CP 152   // LDS row stride in bf16 elems (304B = 19*16: b128-aligned rows,
                 // dword stride 76 ≡ 12 mod 32 -> frag ds_read_b128 at bank floor)

typedef unsigned short u16;
typedef u16 u16x8 __attribute__((ext_vector_type(8)));
typedef u16 u16x4 __attribute__((ext_vector_type(4)));
typedef __bf16 bf16x8 __attribute__((ext_vector_type(8)));
typedef float f32x4 __attribute__((ext_vector_type(4)));

__device__ __forceinline__ u16 f2b(float f) {
    unsigned int u = __float_as_uint(f);
    u += 0x7FFFu + ((u >> 16) & 1u);   // RNE
    return (u16)(u >> 16);
}
__device__ __forceinline__ float b2f(u16 u) {
    return __uint_as_float(((unsigned int)u) << 16);
}

// ---------- MFMA helpers ----------
// A-frag (weights): lane l holds W[16*ot + (l&15)][32*kk + 8*(l>>4) + j], j=0..7,
// pre-packed by k_wcvt at WB[((ot*4+kk)*64 + l)*8].
// B-frag (acts): lane l holds x[n0 + (l&15)][32*kk + 8*(l>>4) + j] from LDS [n][c].
__device__ __forceinline__ void loadB(const u16* brow, int g, bf16x8 bfr[4]) {
#pragma unroll
    for (int kk = 0; kk < 4; ++kk)
        bfr[kk] = *(const bf16x8*)(brow + kk * 32 + g * 8);
}
__device__ __forceinline__ bf16x8 ldA(const u16* __restrict__ WB, int ot, int kk, int l) {
    return *(const bf16x8*)(WB + ((size_t)(ot * 4 + kk) * 64 + l) * 8);
}

// ---------- kernel -1: compose weights (fp32): Wqe=Wq*We, Wkd=Wk*Wd, Wvd=Wv*Wd ----------
__global__ __launch_bounds__(128) void k_comp(
    const float* __restrict__ Wq, const float* __restrict__ Wk,
    const float* __restrict__ Wv, const float* __restrict__ We,
    const float* __restrict__ Wd, const float* __restrict__ be,
    const float* __restrict__ bd,
    float* __restrict__ Wcomp, float* __restrict__ cvec)
{
    const int mat = blockIdx.y, o = blockIdx.x, c = threadIdx.x;
    const float* A = (mat == 0) ? Wq : (mat == 1) ? Wk : Wv;
    const float* B = (mat == 0) ? We : Wd;
    const float* bv = (mat == 0) ? be : bd;
    float acc = 0.f;
    for (int m = 0; m < CC; ++m) acc += A[o * CC + m] * B[m * CC + c];
    Wcomp[(size_t)mat * 16384 + o * CC + c] = acc;
    if (c == 0) {
        float bacc = 0.f;
        for (int m = 0; m < CC; ++m) bacc += A[o * CC + m] * bv[m];
        cvec[mat * CC + o] = bacc;
    }
}

// ---------- kernel 0: pack 6 weight matrices into bf16 frag order ----------
__global__ __launch_bounds__(256) void k_wcvt(
    const float* __restrict__ W0, const float* __restrict__ W1,
    const float* __restrict__ W2, const float* __restrict__ W3,
    const float* __restrict__ W4, const float* __restrict__ W5,
    u16* __restrict__ out)
{
    const int gid = blockIdx.x * 256 + threadIdx.x;  // 6*2048
    const int wi = gid >> 11, rem = gid & 2047;
    const float* W = (wi == 0) ? W0 : (wi == 1) ? W1 : (wi == 2) ? W2
                   : (wi == 3) ? W3 : (wi == 4) ? W4 : W5;
    const int ot = rem >> 8, kk = (rem >> 6) & 3, l = rem & 63;
    const int row = ot * 16 + (l & 15), col = kk * 32 + (l >> 4) * 8;
    float4 a = *(const float4*)(W + row * CC + col);
    float4 b = *(const float4*)(W + row * CC + col + 4);
    u16x8 u;
    u[0] = f2b(a.x); u[1] = f2b(a.y); u[2] = f2b(a.z); u[3] = f2b(a.w);
    u[4] = f2b(b.x); u[5] = f2b(b.y); u[6] = f2b(b.z); u[7] = f2b(b.w);
    *(u16x8*)(out + (size_t)wi * 16384 + ((size_t)(ot * 4 + kk) * 64 + l) * 8) = u;
}

// ---------- kernel 1: front — 5 INDEPENDENT MFMA GEMMs from staged inputs ----------
__global__ __launch_bounds__(256) void k_front(
    const float* __restrict__ edge, const float* __restrict__ dvs,
    const u16* __restrict__ WeB, const u16* __restrict__ WdB,
    const u16* __restrict__ WqeB, const u16* __restrict__ WkdB,
    const u16* __restrict__ WvdB,
    const float* __restrict__ be, const float* __restrict__ bd,
    const float* __restrict__ bq,
    const float* __restrict__ cq, const float* __restrict__ ck,
    const float* __restrict__ cv,
    float* __restrict__ l2e_out,
    u16* __restrict__ qT, u16* __restrict__ kT, u16* __restrict__ vT)
{
    __shared__ u16 bufA[64 * CP];
    __shared__ u16 bufB[64 * CP];
    const int t = threadIdx.x;
    const int bt = blockIdx.y;
    const int n0b = blockIdx.x * 64;
    const float* eb = edge + (size_t)bt * CC * NN + n0b;
    const float* db = dvs + (size_t)bt * CC * NN + n0b;

    // stage: transpose [c][n] fp32 -> [n][c] bf16
#pragma unroll
    for (int j = 0; j < 2; ++j) {
        const int i = t + 256 * j;
        const int c4 = i >> 4, p = i & 15;
        float4 e[4], d[4];
#pragma unroll
        for (int m = 0; m < 4; ++m) {
            e[m] = *(const float4*)(eb + (size_t)(4 * c4 + m) * NN + 4 * p);
            d[m] = *(const float4*)(db + (size_t)(4 * c4 + m) * NN + 4 * p);
        }
#pragma unroll
        for (int n = 0; n < 4; ++n) {
            u16x4 ue, ud;
            ue[0] = f2b(((const float*)&e[0])[n]); ud[0] = f2b(((const float*)&d[0])[n]);
            ue[1] = f2b(((const float*)&e[1])[n]); ud[1] = f2b(((const float*)&d[1])[n]);
            ue[2] = f2b(((const float*)&e[2])[n]); ud[2] = f2b(((const float*)&d[2])[n]);
            ue[3] = f2b(((const float*)&e[3])[n]); ud[3] = f2b(((const float*)&d[3])[n]);
            *(u16x4*)&bufA[(4 * p + n) * CP + 4 * c4] = ue;
            *(u16x4*)&bufB[(4 * p + n) * CP + 4 * c4] = ud;
        }
    }
    __syncthreads();  // only barrier

    const int l = t & 63, w = t >> 6;
    const int l15 = l & 15, g = l >> 4;
    const int nloc = w * 16 + l15;
    const size_t gn = (size_t)bt * NN + n0b + nloc;

    bf16x8 bfrE[4], bfrD[4];
    loadB(bufA + nloc * CP, g, bfrE);
    loadB(bufB + nloc * CP, g, bfrD);

    // --- ef/df accumulators (never materialized; stats only) ---
    f32x4 aE[8], aD[8];
#pragma unroll
    for (int ot = 0; ot < 8; ++ot) {
        aE[ot] = *(const f32x4*)(be + 16 * ot + 4 * g);
        aD[ot] = *(const f32x4*)(bd + 16 * ot + 4 * g);
    }
#pragma unroll
    for (int ot = 0; ot < 8; ++ot)
#pragma unroll
        for (int kk = 0; kk < 4; ++kk) {
            aE[ot] = __builtin_amdgcn_mfma_f32_16x16x32_bf16(ldA(WeB, ot, kk, l), bfrE[kk], aE[ot], 0, 0, 0);
            aD[ot] = __builtin_amdgcn_mfma_f32_16x16x32_bf16(ldA(WdB, ot, kk, l), bfrD[kk], aD[ot], 0, 0, 0);
        }
    // --- stats (fp32 accs -> sim, l2e) ---
    float s2e = 0.f, s2d = 0.f, sed = 0.f;
#pragma unroll
    for (int ot = 0; ot < 8; ++ot)
#pragma unroll
        for (int r = 0; r < 4; ++r) {
            const float fe = aE[ot][r], fd = aD[ot][r];
            s2e += fe * fe; s2d += fd * fd; sed += fe * fd;
        }
    s2e += __shfl_xor(s2e, 16); s2e += __shfl_xor(s2e, 32);
    s2d += __shfl_xor(s2d, 16); s2d += __shfl_xor(s2d, 32);
    sed += __shfl_xor(sed, 16); sed += __shfl_xor(sed, 32);
    const float le = sqrtf(s2e), ld = sqrtf(s2d);
    const float sim = (sed / ((le + 1e-6f) * (ld + 1e-6f)) + 1.0f) * 0.5f;
    if (g == 0) l2e_out[gn] = le;

    // --- q = sim*(Wqe*e + cq) + bq ---
    {
        f32x4 aQ[8];
#pragma unroll
        for (int ot = 0; ot < 8; ++ot) aQ[ot] = *(const f32x4*)(cq + 16 * ot + 4 * g);
#pragma unroll
        for (int ot = 0; ot < 8; ++ot)
#pragma unroll
            for (int kk = 0; kk < 4; ++kk)
                aQ[ot] = __builtin_amdgcn_mfma_f32_16x16x32_bf16(ldA(WqeB, ot, kk, l), bfrE[kk], aQ[ot], 0, 0, 0);
#pragma unroll
        for (int ot = 0; ot < 8; ++ot) {
            f32x4 b4 = *(const f32x4*)(bq + 16 * ot + 4 * g);
            u16x4 u;
#pragma unroll
            for (int r = 0; r < 4; ++r) u[r] = f2b(sim * aQ[ot][r] + b4[r]);
            *(u16x4*)(qT + gn * CC + 16 * ot + 4 * g) = u;
        }
    }
    // --- kraw = Wkd*d + ck  (dens & bk applied in k_attn) ---
    {
        f32x4 aK[8];
#pragma unroll
        for (int ot = 0; ot < 8; ++ot) aK[ot] = *(const f32x4*)(ck + 16 * ot + 4 * g);
#pragma unroll
        for (int ot = 0; ot < 8; ++ot)
#pragma unroll
            for (int kk = 0; kk < 4; ++kk)
                aK[ot] = __builtin_amdgcn_mfma_f32_16x16x32_bf16(ldA(WkdB, ot, kk, l), bfrD[kk], aK[ot], 0, 0, 0);
#pragma unroll
        for (int ot = 0; ot < 8; ++ot) {
            u16x4 u;
#pragma unroll
            for (int r = 0; r < 4; ++r) u[r] = f2b(aK[ot][r]);
            *(u16x4*)(kT + gn * CC + 16 * ot + 4 * g) = u;
        }
    }
    // --- vraw = Wvd*d + cv ---
    {
        f32x4 aV[8];
#pragma unroll
        for (int ot = 0; ot < 8; ++ot) aV[ot] = *(const f32x4*)(cv + 16 * ot + 4 * g);
#pragma unroll
        for (int ot = 0; ot < 8; ++ot)
#pragma unroll
            for (int kk = 0; kk < 4; ++kk)
                aV[ot] = __builtin_amdgcn_mfma_f32_16x16x32_bf16(ldA(WvdB, ot, kk, l), bfrD[kk], aV[ot], 0, 0, 0);
#pragma unroll
        for (int ot = 0; ot < 8; ++ot) {
            u16x4 u;
#pragma unroll
            for (int r = 0; r < 4; ++r) u[r] = f2b(aV[ot][r]);
            *(u16x4*)(vT + gn * CC + 16 * ot + 4 * g) = u;
        }
    }
}

// ---------- kernel 2: spatial softmax of l2e -> density ----------
__global__ __launch_bounds__(256) void k_dens(const float* __restrict__ l2e,
                                              float* __restrict__ dens)
{
    __shared__ float red1[4];
    __shared__ float red2[4];
    const int bt = blockIdx.x, t = threadIdx.x;
    const int lane = t & 63, wid = t >> 6;
    const float* x = l2e + (size_t)bt * NN;
    float v[4], m = -1e30f;
#pragma unroll
    for (int i = 0; i < 4; ++i) { v[i] = x[t + 256 * i]; m = fmaxf(m, v[i]); }
#pragma unroll
    for (int off = 32; off >= 1; off >>= 1) m = fmaxf(m, __shfl_xor(m, off));
    if (lane == 0) red1[wid] = m;
    __syncthreads();
    m = fmaxf(fmaxf(red1[0], red1[1]), fmaxf(red1[2], red1[3]));
    float e[4], s = 0.f;
#pragma unroll
    for (int i = 0; i < 4; ++i) { e[i] = expf(v[i] - m); s += e[i]; }
#pragma unroll
    for (int off = 32; off >= 1; off >>= 1) s += __shfl_xor(s, off);
    if (lane == 0) red2[wid] = s;
    __syncthreads();
    s = red2[0] + red2[1] + red2[2] + red2[3];
    const float scale = 1024.0f / s;
#pragma unroll
    for (int i = 0; i < 4; ++i) dens[(size_t)bt * NN + t + 256 * i] = e[i] * scale;
}

// ---------- kernel 3: windowed attention (bf16 in/out) ----------
__global__ __launch_bounds__(256) void k_attn(
    const u16* __restrict__ qT, const u16* __restrict__ kT,
    const u16* __restrict__ vT, const float* __restrict__ dens,
    const float* __restrict__ bk, const float* __restrict__ bv,
    u16* __restrict__ attT)
{
    __shared__ float4 q_s[32 * 32];
    __shared__ float4 kv_s[32 * 32];
    __shared__ float sc[49][33];
    __shared__ float red[8][33];
    const int t = threadIdx.x;
    const int qx = blockIdx.x;
    const int bt = blockIdx.y;
    const int qy = t & 31, kg = t >> 5;
    const int kxmin = max(qx - 3, 0), kxmax = min(qx + 3, 31);
    const int NKX = kxmax - kxmin + 1;
    const int J = NKX * 7;

#pragma unroll
    for (int j = 0; j < 2; ++j) {
        const int i = t + 256 * j;
        const int row = i >> 4, s8 = i & 15;
        u16x8 u = *(const u16x8*)(qT + ((size_t)bt * NN + qx * 32 + row) * CC + 8 * s8);
        float4 lo, hi;
        lo.x = b2f(u[0]); lo.y = b2f(u[1]); lo.z = b2f(u[2]); lo.w = b2f(u[3]);
        hi.x = b2f(u[4]); hi.y = b2f(u[5]); hi.z = b2f(u[6]); hi.w = b2f(u[7]);
        q_s[(row << 5) | ((2 * s8) ^ row)] = lo;
        q_s[(row << 5) | ((2 * s8 + 1) ^ row)] = hi;
    }

    // ---- pass A: scores (k = dens*kraw + bk applied on stage) ----
    for (int kxi = 0; kxi < NKX; ++kxi) {
        const int kx = kxmin + kxi;
        __syncthreads();
        {
            const u16* gb = kT + ((size_t)bt * NN + kx * 32) * CC;
            const float* dr = dens + (size_t)bt * NN + kx * 32;
#pragma unroll
            for (int j = 0; j < 2; ++j) {
                const int i = t + 256 * j;
                const int row = i >> 4, s8 = i & 15;
                u16x8 u = *(const u16x8*)(gb + (size_t)row * CC + 8 * s8);
                const float dn = dr[row];
                f32x4 b0 = *(const f32x4*)(bk + 8 * s8);
                f32x4 b1 = *(const f32x4*)(bk + 8 * s8 + 4);
                float4 lo, hi;
                lo.x = dn * b2f(u[0]) + b0[0]; lo.y = dn * b2f(u[1]) + b0[1];
                lo.z = dn * b2f(u[2]) + b0[2]; lo.w = dn * b2f(u[3]) + b0[3];
                hi.x = dn * b2f(u[4]) + b1[0]; hi.y = dn * b2f(u[5]) + b1[1];
                hi.z = dn * b2f(u[6]) + b1[2]; hi.w = dn * b2f(u[7]) + b1[3];
                kv_s[(row << 5) | ((2 * s8) ^ row)] = lo;
                kv_s[(row << 5) | ((2 * s8 + 1) ^ row)] = hi;
            }
        }
        __syncthreads();
        if (kg < 7) {
            const int ky = qy + kg - 3;
            const int kyc = min(max(ky, 0), 31);
            const int qb = qy << 5, kb = kyc << 5;
            float acc = 0.f;
#pragma unroll
            for (int s = 0; s < 32; ++s) {
                float4 qv = q_s[qb | (s ^ qy)];
                float4 kv = kv_s[kb | (s ^ kyc)];
                acc += qv.x * kv.x + qv.y * kv.y + qv.z * kv.z + qv.w * kv.w;
            }
            sc[kxi * 7 + kg][qy] =
                (ky == kyc) ? acc * 0.08838834764831843f : -1e30f;
        }
    }
    __syncthreads();

    // ---- softmax ----
    float m = -1e30f;
    for (int j = kg; j < J; j += 8) m = fmaxf(m, sc[j][qy]);
    red[kg][qy] = m;
    __syncthreads();
    m = red[0][qy];
#pragma unroll
    for (int i = 1; i < 8; ++i) m = fmaxf(m, red[i][qy]);
    __syncthreads();
    float ps = 0.f;
    for (int j = kg; j < J; j += 8) {
        float e = expf(sc[j][qy] - m);
        sc[j][qy] = e;
        ps += e;
    }
    red[kg][qy] = ps;
    __syncthreads();
    float S = 0.f;
#pragma unroll
    for (int i = 0; i < 8; ++i) S += red[i][qy];
    const float inv = 1.0f / S;

    // ---- pass B: PV (v = dens*vraw + bv on stage) ----
    const int cg = kg;
    float4 a0 = {0, 0, 0, 0}, a1 = {0, 0, 0, 0}, a2 = {0, 0, 0, 0}, a3 = {0, 0, 0, 0};
    for (int kxi = 0; kxi < NKX; ++kxi) {
        const int kx = kxmin + kxi;
        __syncthreads();
        {
            const u16* gb = vT + ((size_t)bt * NN + kx * 32) * CC;
            const float* dr = dens + (size_t)bt * NN + kx * 32;
#pragma unroll
            for (int j = 0; j < 2; ++j) {
                const int i = t + 256 * j;
                const int row = i >> 4, s8 = i & 15;
                u16x8 u = *(const u16x8*)(gb + (size_t)row * CC + 8 * s8);
                const float dn = dr[row];
                f32x4 b0 = *(const f32x4*)(bv + 8 * s8);
                f32x4 b1 = *(const f32x4*)(bv + 8 * s8 + 4);
                float4 lo, hi;
                lo.x = dn * b2f(u[0]) + b0[0]; lo.y = dn * b2f(u[1]) + b0[1];
                lo.z = dn * b2f(u[2]) + b0[2]; lo.w = dn * b2f(u[3]) + b0[3];
                hi.x = dn * b2f(u[4]) + b1[0]; hi.y = dn * b2f(u[5]) + b1[1];
                hi.z = dn * b2f(u[6]) + b1[2]; hi.w = dn * b2f(u[7]) + b1[3];
                kv_s[(row << 5) | ((2 * s8) ^ row)] = lo;
                kv_s[(row << 5) | ((2 * s8 + 1) ^ row)] = hi;
            }
        }
        __syncthreads();
#pragma unroll
        for (int dy = 0; dy < 7; ++dy) {
            const int ky = qy + dy - 3;
            const int kyc = min(max(ky, 0), 31);
            const float wgt = sc[kxi * 7 + dy][qy];  // exactly 0 for OOB
            const int rb = kyc << 5;
            float4 v0 = kv_s[rb | ((4 * cg + 0) ^ kyc)];
            float4 v1 = kv_s[rb | ((4 * cg + 1) ^ kyc)];
            float4 v2 = kv_s[rb | ((4 * cg + 2) ^ kyc)];
            float4 v3 = kv_s[rb | ((4 * cg + 3) ^ kyc)];
            a0.x += wgt * v0.x; a0.y += wgt * v0.y; a0.z += wgt * v0.z; a0.w += wgt * v0.w;
            a1.x += wgt * v1.x; a1.y += wgt * v1.y; a1.z += wgt * v1.z; a1.w += wgt * v1.w;
            a2.x += wgt * v2.x; a2.y += wgt * v2.y; a2.z += wgt * v2.z; a2.w += wgt * v2.w;
            a3.x += wgt * v3.x; a3.y += wgt * v3.y; a3.z += wgt * v3.z; a3.w += wgt * v3.w;
        }
    }
    const int qn = qx * 32 + qy;
    u16* ob = attT + ((size_t)bt * NN + qn) * CC + cg * 16;
    float vals[16] = {a0.x, a0.y, a0.z, a0.w, a1.x, a1.y, a1.z, a1.w,
                      a2.x, a2.y, a2.z, a2.w, a3.x, a3.y, a3.z, a3.w};
    u16x8 o0, o1;
#pragma unroll
    for (int j = 0; j < 8; ++j) { o0[j] = f2b(vals[j] * inv); o1[j] = f2b(vals[8 + j] * inv); }
    *(u16x8*)ob = o0;
    *(u16x8*)(ob + 8) = o1;
}

// ---------- kernel 4: fused output conv + LIF scan (direct global B-frags) ----------
__global__ __launch_bounds__(128) void k_flif(
    const u16* __restrict__ attT, const u16* __restrict__ WfB,
    const float* __restrict__ bf, float* __restrict__ out)
{
    __shared__ float spk[128 * 36];
    const int t = threadIdx.x;
    const int n0b = blockIdx.x * 32;
    const int b = blockIdx.y;
    const int l = t & 63, w = t >> 6;
    const int l15 = l & 15, g = l >> 4;
    const int nloc = w * 16 + l15;
    f32x4 mem[8];
#pragma unroll
    for (int ot = 0; ot < 8; ++ot) mem[ot] = (f32x4){0.f, 0.f, 0.f, 0.f};

    for (int tt = 0; tt < 4; ++tt) {
        const u16* brow = attT + ((size_t)(b * 4 + tt) * NN + n0b + nloc) * CC;
        bf16x8 bfr[4];
#pragma unroll
        for (int kk = 0; kk < 4; ++kk)
            bfr[kk] = *(const bf16x8*)(brow + kk * 32 + g * 8);
#pragma unroll
        for (int ot = 0; ot < 8; ++ot) {
            f32x4 a = *(const f32x4*)(bf + 16 * ot + 4 * g);
#pragma unroll
            for (int kk = 0; kk < 4; ++kk)
                a = __builtin_amdgcn_mfma_f32_16x16x32_bf16(
                    *(const bf16x8*)(WfB + ((size_t)(ot * 4 + kk) * 64 + l) * 8),
                    bfr[kk], a, 0, 0, 0);
            f32x4 mv = mem[ot] * 0.5f + a;
#pragma unroll
            for (int r = 0; r < 4; ++r) {
                const float s = (mv[r] > 1.0f) ? 1.0f : 0.0f;
                spk[(16 * ot + 4 * g + r) * 36 + nloc] = s;
                if (mv[r] > 1.0f) mv[r] = 0.f;
            }
            mem[ot] = mv;
        }
        __syncthreads();
#pragma unroll
        for (int j = 0; j < 8; ++j) {
            const int i = t + 128 * j;
            const int row = i >> 3, n4 = (i & 7) * 4;
            *(float4*)(out + ((size_t)(b * 4 + tt) * CC + row) * NN + n0b + n4) =
                *(const float4*)&spk[row * 36 + n4];
        }
        __syncthreads();
    }
}

extern "C" void kernel_launch(void* const* d_in, const int* in_sizes, int n_in,
                              void* d_out, int out_size, void* d_ws, size_t ws_size,
                              hipStream_t stream) {
    (void)in_sizes; (void)n_in; (void)out_size; (void)ws_size;
    const float* edge = (const float*)d_in[0];
    const float* dvs  = (const float*)d_in[1];
    const float* We = (const float*)d_in[2];
    const float* be = (const float*)d_in[3];
    const float* Wd = (const float*)d_in[4];
    const float* bd = (const float*)d_in[5];
    const float* Wq = (const float*)d_in[6];
    const float* bq = (const float*)d_in[7];
    const float* Wk = (const float*)d_in[8];
    const float* bk = (const float*)d_in[9];
    const float* Wv = (const float*)d_in[10];
    const float* bv = (const float*)d_in[11];
    const float* Wf = (const float*)d_in[12];
    const float* bf = (const float*)d_in[13];
    float* out = (float*)d_out;

    const size_t S = (size_t)BTOT * NN * CC;  // 4.19M elems
    u16* qT   = (u16*)d_ws;
    u16* kT   = qT + S;
    u16* vT   = kT + S;
    u16* attT = vT + S;
    u16* WbAll = attT + S;                    // 6 * 16384 u16
    float* fbase = (float*)(WbAll + 6 * 16384);
    float* Wcomp = fbase;                     // 3 * 16384 f32
    float* cvec  = Wcomp + 3 * 16384;         // 3 * 128
    float* l2e   = cvec + 3 * CC;
    float* dens  = l2e + BTOT * NN;
    u16* WeB  = WbAll + 0 * 16384;
    u16* WdB  = WbAll + 1 * 16384;
    u16* WqeB = WbAll + 2 * 16384;
    u16* WkdB = WbAll + 3 * 16384;
    u16* WvdB = WbAll + 4 * 16384;
    u16* WfB  = WbAll + 5 * 16384;
    float* cq = cvec;
    float* ck = cvec + CC;
    float* cv = cvec + 2 * CC;

    k_comp<<<dim3(128, 3), 128, 0, stream>>>(Wq, Wk, Wv, We, Wd, be, bd, Wcomp, cvec);
    k_wcvt<<<48, 256, 0, stream>>>(We, Wd, Wcomp, Wcomp + 16384, Wcomp + 32768, Wf, WbAll);
    k_front<<<dim3(16, BTOT), 256, 0, stream>>>(edge, dvs, WeB, WdB, WqeB, WkdB, WvdB,
                                                be, bd, bq, cq, ck, cv, l2e, qT, kT, vT);
    k_dens<<<BTOT, 256, 0, stream>>>(l2e, dens);
    k_attn<<<dim3(32, BTOT), 256, 0, stream>>>(qT, kT, vT, dens, bk, bv, attT);
    k_flif<<<dim3(32, 8), 128, 0, stream>>>(attT, WfB, bf, out);
}

// Round 6
// 71.424 us; speedup vs baseline: 5.4025x; 1.2554x over previous
//
#include <hip/hip_runtime.h>
#include <math.h>

#define CC 128   // channels
#define NN 1024  // H*W
#define BTOT 32  // B*T
#define CP 152   // k_front LDS row stride (bf16 elems)
#define PST 232  // P_lds row stride (bf16 elems): 464B row -> 2-way bank alias only

typedef unsigned short u16;
typedef u16 u16x8 __attribute__((ext_vector_type(8)));
typedef u16 u16x4 __attribute__((ext_vector_type(4)));
typedef __bf16 bf16x8 __attribute__((ext_vector_type(8)));
typedef float f32x4 __attribute__((ext_vector_type(4)));

__device__ __forceinline__ u16 f2b(float f) {
    unsigned int u = __float_as_uint(f);
    u += 0x7FFFu + ((u >> 16) & 1u);   // RNE
    return (u16)(u >> 16);
}
__device__ __forceinline__ float b2f(u16 u) {
    return __uint_as_float(((unsigned int)u) << 16);
}

// ---------- MFMA helpers ----------
// A-frag: lane l holds A[16*ot + (l&15)][32*kk + 8*(l>>4) + j], j=0..7.
// B-frag: lane l holds B[16*nt + (l&15)][32*kk + 8*(l>>4) + j].
// D = A*B^T, C/D layout: col = l&15 (B row), row = (l>>4)*4 + r (+16*ot) (A row).
__device__ __forceinline__ void loadB(const u16* brow, int g, bf16x8 bfr[4]) {
#pragma unroll
    for (int kk = 0; kk < 4; ++kk)
        bfr[kk] = *(const bf16x8*)(brow + kk * 32 + g * 8);
}
__device__ __forceinline__ bf16x8 ldA(const u16* __restrict__ WB, int ot, int kk, int l) {
    return *(const bf16x8*)(WB + ((size_t)(ot * 4 + kk) * 64 + l) * 8);
}

// ---------- kernel -1: compose weights (fp32): Wqe=Wq*We, Wkd=Wk*Wd, Wvd=Wv*Wd ----------
__global__ __launch_bounds__(128) void k_comp(
    const float* __restrict__ Wq, const float* __restrict__ Wk,
    const float* __restrict__ Wv, const float* __restrict__ We,
    const float* __restrict__ Wd, const float* __restrict__ be,
    const float* __restrict__ bd,
    float* __restrict__ Wcomp, float* __restrict__ cvec)
{
    const int mat = blockIdx.y, o = blockIdx.x, c = threadIdx.x;
    const float* A = (mat == 0) ? Wq : (mat == 1) ? Wk : Wv;
    const float* B = (mat == 0) ? We : Wd;
    const float* bv = (mat == 0) ? be : bd;
    float acc = 0.f;
    for (int m = 0; m < CC; ++m) acc += A[o * CC + m] * B[m * CC + c];
    Wcomp[(size_t)mat * 16384 + o * CC + c] = acc;
    if (c == 0) {
        float bacc = 0.f;
        for (int m = 0; m < CC; ++m) bacc += A[o * CC + m] * bv[m];
        cvec[mat * CC + o] = bacc;
    }
}

// ---------- kernel 0: pack 6 weight matrices into bf16 frag order ----------
__global__ __launch_bounds__(256) void k_wcvt(
    const float* __restrict__ W0, const float* __restrict__ W1,
    const float* __restrict__ W2, const float* __restrict__ W3,
    const float* __restrict__ W4, const float* __restrict__ W5,
    u16* __restrict__ out)
{
    const int gid = blockIdx.x * 256 + threadIdx.x;  // 6*2048
    const int wi = gid >> 11, rem = gid & 2047;
    const float* W = (wi == 0) ? W0 : (wi == 1) ? W1 : (wi == 2) ? W2
                   : (wi == 3) ? W3 : (wi == 4) ? W4 : W5;
    const int ot = rem >> 8, kk = (rem >> 6) & 3, l = rem & 63;
    const int row = ot * 16 + (l & 15), col = kk * 32 + (l >> 4) * 8;
    float4 a = *(const float4*)(W + row * CC + col);
    float4 b = *(const float4*)(W + row * CC + col + 4);
    u16x8 u;
    u[0] = f2b(a.x); u[1] = f2b(a.y); u[2] = f2b(a.z); u[3] = f2b(a.w);
    u[4] = f2b(b.x); u[5] = f2b(b.y); u[6] = f2b(b.z); u[7] = f2b(b.w);
    *(u16x8*)(out + (size_t)wi * 16384 + ((size_t)(ot * 4 + kk) * 64 + l) * 8) = u;
}

// ---------- kernel 1: front — 5 independent MFMA GEMMs from staged inputs ----------
__global__ __launch_bounds__(256) void k_front(
    const float* __restrict__ edge, const float* __restrict__ dvs,
    const u16* __restrict__ WeB, const u16* __restrict__ WdB,
    const u16* __restrict__ WqeB, const u16* __restrict__ WkdB,
    const u16* __restrict__ WvdB,
    const float* __restrict__ be, const float* __restrict__ bd,
    const float* __restrict__ bq,
    const float* __restrict__ cq, const float* __restrict__ ck,
    const float* __restrict__ cv,
    float* __restrict__ l2e_out,
    u16* __restrict__ qT, u16* __restrict__ kT, u16* __restrict__ vN)
{
    __shared__ u16 bufA[64 * CP];
    __shared__ u16 bufB[64 * CP];
    const int t = threadIdx.x;
    const int bt = blockIdx.y;
    const int n0b = blockIdx.x * 64;
    const float* eb = edge + (size_t)bt * CC * NN + n0b;
    const float* db = dvs + (size_t)bt * CC * NN + n0b;

    // stage: transpose [c][n] fp32 -> [n][c] bf16
#pragma unroll
    for (int j = 0; j < 2; ++j) {
        const int i = t + 256 * j;
        const int c4 = i >> 4, p = i & 15;
        float4 e[4], d[4];
#pragma unroll
        for (int m = 0; m < 4; ++m) {
            e[m] = *(const float4*)(eb + (size_t)(4 * c4 + m) * NN + 4 * p);
            d[m] = *(const float4*)(db + (size_t)(4 * c4 + m) * NN + 4 * p);
        }
#pragma unroll
        for (int n = 0; n < 4; ++n) {
            u16x4 ue, ud;
            ue[0] = f2b(((const float*)&e[0])[n]); ud[0] = f2b(((const float*)&d[0])[n]);
            ue[1] = f2b(((const float*)&e[1])[n]); ud[1] = f2b(((const float*)&d[1])[n]);
            ue[2] = f2b(((const float*)&e[2])[n]); ud[2] = f2b(((const float*)&d[2])[n]);
            ue[3] = f2b(((const float*)&e[3])[n]); ud[3] = f2b(((const float*)&d[3])[n]);
            *(u16x4*)&bufA[(4 * p + n) * CP + 4 * c4] = ue;
            *(u16x4*)&bufB[(4 * p + n) * CP + 4 * c4] = ud;
        }
    }
    __syncthreads();  // only barrier

    const int l = t & 63, w = t >> 6;
    const int l15 = l & 15, g = l >> 4;
    const int nloc = w * 16 + l15;
    const size_t gn = (size_t)bt * NN + n0b + nloc;

    bf16x8 bfrE[4], bfrD[4];
    loadB(bufA + nloc * CP, g, bfrE);
    loadB(bufB + nloc * CP, g, bfrD);

    // --- ef/df accumulators (stats only, never materialized) ---
    f32x4 aE[8], aD[8];
#pragma unroll
    for (int ot = 0; ot < 8; ++ot) {
        aE[ot] = *(const f32x4*)(be + 16 * ot + 4 * g);
        aD[ot] = *(const f32x4*)(bd + 16 * ot + 4 * g);
    }
#pragma unroll
    for (int ot = 0; ot < 8; ++ot)
#pragma unroll
        for (int kk = 0; kk < 4; ++kk) {
            aE[ot] = __builtin_amdgcn_mfma_f32_16x16x32_bf16(ldA(WeB, ot, kk, l), bfrE[kk], aE[ot], 0, 0, 0);
            aD[ot] = __builtin_amdgcn_mfma_f32_16x16x32_bf16(ldA(WdB, ot, kk, l), bfrD[kk], aD[ot], 0, 0, 0);
        }
    float s2e = 0.f, s2d = 0.f, sed = 0.f;
#pragma unroll
    for (int ot = 0; ot < 8; ++ot)
#pragma unroll
        for (int r = 0; r < 4; ++r) {
            const float fe = aE[ot][r], fd = aD[ot][r];
            s2e += fe * fe; s2d += fd * fd; sed += fe * fd;
        }
    s2e += __shfl_xor(s2e, 16); s2e += __shfl_xor(s2e, 32);
    s2d += __shfl_xor(s2d, 16); s2d += __shfl_xor(s2d, 32);
    sed += __shfl_xor(sed, 16); sed += __shfl_xor(sed, 32);
    const float le = sqrtf(s2e), ld = sqrtf(s2d);
    const float sim = (sed / ((le + 1e-6f) * (ld + 1e-6f)) + 1.0f) * 0.5f;
    if (g == 0) l2e_out[gn] = le;

    // --- q = sim*(Wqe*e + cq) + bq ---
    {
        f32x4 aQ[8];
#pragma unroll
        for (int ot = 0; ot < 8; ++ot) aQ[ot] = *(const f32x4*)(cq + 16 * ot + 4 * g);
#pragma unroll
        for (int ot = 0; ot < 8; ++ot)
#pragma unroll
            for (int kk = 0; kk < 4; ++kk)
                aQ[ot] = __builtin_amdgcn_mfma_f32_16x16x32_bf16(ldA(WqeB, ot, kk, l), bfrE[kk], aQ[ot], 0, 0, 0);
#pragma unroll
        for (int ot = 0; ot < 8; ++ot) {
            f32x4 b4 = *(const f32x4*)(bq + 16 * ot + 4 * g);
            u16x4 u;
#pragma unroll
            for (int r = 0; r < 4; ++r) u[r] = f2b(sim * aQ[ot][r] + b4[r]);
            *(u16x4*)(qT + gn * CC + 16 * ot + 4 * g) = u;
        }
    }
    // --- kraw = Wkd*d + ck  (dens & bk folded into k_attn) ---
    {
        f32x4 aK[8];
#pragma unroll
        for (int ot = 0; ot < 8; ++ot) aK[ot] = *(const f32x4*)(ck + 16 * ot + 4 * g);
#pragma unroll
        for (int ot = 0; ot < 8; ++ot)
#pragma unroll
            for (int kk = 0; kk < 4; ++kk)
                aK[ot] = __builtin_amdgcn_mfma_f32_16x16x32_bf16(ldA(WkdB, ot, kk, l), bfrD[kk], aK[ot], 0, 0, 0);
#pragma unroll
        for (int ot = 0; ot < 8; ++ot) {
            u16x4 u;
#pragma unroll
            for (int r = 0; r < 4; ++r) u[r] = f2b(aK[ot][r]);
            *(u16x4*)(kT + gn * CC + 16 * ot + 4 * g) = u;
        }
    }
    // --- vraw = Wvd*d + cv ; stored CHANNEL-MAJOR vN[c][n] for PV A-frags ---
    {
        f32x4 aV[8];
#pragma unroll
        for (int ot = 0; ot < 8; ++ot) aV[ot] = *(const f32x4*)(cv + 16 * ot + 4 * g);
#pragma unroll
        for (int ot = 0; ot < 8; ++ot)
#pragma unroll
            for (int kk = 0; kk < 4; ++kk)
                aV[ot] = __builtin_amdgcn_mfma_f32_16x16x32_bf16(ldA(WvdB, ot, kk, l), bfrD[kk], aV[ot], 0, 0, 0);
#pragma unroll
        for (int ot = 0; ot < 8; ++ot)
#pragma unroll
            for (int r = 0; r < 4; ++r)
                vN[((size_t)bt * CC + 16 * ot + 4 * g + r) * NN + n0b + nloc] = f2b(aV[ot][r]);
    }
}

// ---------- kernel 2: spatial softmax of l2e -> density ----------
__global__ __launch_bounds__(256) void k_dens(const float* __restrict__ l2e,
                                              float* __restrict__ dens)
{
    __shared__ float red1[4];
    __shared__ float red2[4];
    const int bt = blockIdx.x, t = threadIdx.x;
    const int lane = t & 63, wid = t >> 6;
    const float* x = l2e + (size_t)bt * NN;
    float v[4], m = -1e30f;
#pragma unroll
    for (int i = 0; i < 4; ++i) { v[i] = x[t + 256 * i]; m = fmaxf(m, v[i]); }
#pragma unroll
    for (int off = 32; off >= 1; off >>= 1) m = fmaxf(m, __shfl_xor(m, off));
    if (lane == 0) red1[wid] = m;
    __syncthreads();
    m = fmaxf(fmaxf(red1[0], red1[1]), fmaxf(red1[2], red1[3]));
    float e[4], s = 0.f;
#pragma unroll
    for (int i = 0; i < 4; ++i) { e[i] = expf(v[i] - m); s += e[i]; }
#pragma unroll
    for (int off = 32; off >= 1; off >>= 1) s += __shfl_xor(s, off);
    if (lane == 0) red2[wid] = s;
    __syncthreads();
    s = red2[0] + red2[1] + red2[2] + red2[3];
    const float scale = 1024.0f / s;
#pragma unroll
    for (int i = 0; i < 4; ++i) dens[(size_t)bt * NN + t + 256 * i] = e[i] * scale;
}

// ---------- kernel 3: MFMA windowed attention (swapped QK^T, per-wave job) ----------
// One wave = one (bt, qx). Sᵀ via mfma(K,Q): softmax over kn is lane-local.
// s = (dens[kn]*(q·kraw) + q·bk)/sqrt(C);  P' = e*dens;  out = (P'·vraw)*inv + bv.
__global__ __launch_bounds__(256) void k_attn(
    const u16* __restrict__ qT, const u16* __restrict__ kT,
    const u16* __restrict__ vN, const float* __restrict__ dens,
    const float* __restrict__ bk, const float* __restrict__ bv,
    u16* __restrict__ attT)
{
    __shared__ u16 P_all[4 * 32 * PST];  // 59392 B
    const int t = threadIdx.x;
    const int id = blockIdx.x;
    // XCD-aware: consecutive ids round-robin XCDs; each XCD owns 4 bt values.
    const int bt = (id & 7) * 4 + (id >> 6);
    const int qx = ((id >> 3) & 7) * 4 + (t >> 6);
    const int l = t & 63, l15 = l & 15, g = l >> 4;
    u16* P = P_all + (t >> 6) * 32 * PST;
    const size_t btNN = (size_t)bt * NN;
    const float invsq = 0.08838834764831843f;  // 1/sqrt(128)

    // q fragments (dual u16/bf16 view)
    u16x8 ql[2][4];
#pragma unroll
    for (int nt = 0; nt < 2; ++nt)
#pragma unroll
        for (int kk = 0; kk < 4; ++kk)
            ql[nt][kk] = *(const u16x8*)(qT + (btNN + qx * 32 + 16 * nt + l15) * CC + 32 * kk + 8 * g);

    // qbk[nt] = q[qy]·bk  (frag-partial, reduce over g-groups)
    float qbk[2] = {0.f, 0.f};
#pragma unroll
    for (int kk = 0; kk < 4; ++kk) {
        f32x4 b0 = *(const f32x4*)(bk + 32 * kk + 8 * g);
        f32x4 b1 = *(const f32x4*)(bk + 32 * kk + 8 * g + 4);
#pragma unroll
        for (int nt = 0; nt < 2; ++nt)
#pragma unroll
            for (int j = 0; j < 4; ++j) {
                qbk[nt] += b2f(ql[nt][kk][j]) * b0[j];
                qbk[nt] += b2f(ql[nt][kk][4 + j]) * b1[j];
            }
    }
#pragma unroll
    for (int nt = 0; nt < 2; ++nt) {
        qbk[nt] += __shfl_xor(qbk[nt], 16);
        qbk[nt] += __shfl_xor(qbk[nt], 32);
    }

    // ---- QK^T (swapped) + mask + exp + P' to LDS ----
    float ssum[2] = {0.f, 0.f};
#pragma unroll
    for (int i = 0; i < 7; ++i) {
        const int kxr = qx - 3 + i;
        const int kxc = min(max(kxr, 0), 31);
        const bool cval = (kxr == kxc);
        f32x4 acc[2][2];
#pragma unroll
        for (int mt = 0; mt < 2; ++mt)
#pragma unroll
            for (int nt = 0; nt < 2; ++nt) acc[mt][nt] = (f32x4){0.f, 0.f, 0.f, 0.f};
#pragma unroll
        for (int kk = 0; kk < 4; ++kk)
#pragma unroll
            for (int mt = 0; mt < 2; ++mt) {
                bf16x8 ka = *(const bf16x8*)(kT + (btNN + kxc * 32 + 16 * mt + l15) * CC + 32 * kk + 8 * g);
#pragma unroll
                for (int nt = 0; nt < 2; ++nt)
                    acc[mt][nt] = __builtin_amdgcn_mfma_f32_16x16x32_bf16(
                        ka, __builtin_bit_cast(bf16x8, ql[nt][kk]), acc[mt][nt], 0, 0, 0);
            }
#pragma unroll
        for (int mt = 0; mt < 2; ++mt) {
            f32x4 d4 = *(const f32x4*)(dens + btNN + kxc * 32 + 16 * mt + 4 * g);
#pragma unroll
            for (int nt = 0; nt < 2; ++nt) {
                const int qyv = l15 + 16 * nt;
                u16x4 pw;
#pragma unroll
                for (int r = 0; r < 4; ++r) {
                    const float s = (d4[r] * acc[mt][nt][r] + qbk[nt]) * invsq;
                    const int ky = 16 * mt + 4 * g + r;
                    const int dy = ky - qyv;
                    const bool vld = cval && (dy >= -3) && (dy <= 3);
                    const float e = vld ? __expf(s) : 0.f;
                    ssum[nt] += e;
                    pw[r] = f2b(e * d4[r]);
                }
                *(u16x4*)&P[qyv * PST + i * 32 + 16 * mt + 4 * g] = pw;  // ds_write_b64
            }
        }
    }
    float inv[2];
#pragma unroll
    for (int nt = 0; nt < 2; ++nt) {
        float s = ssum[nt];
        s += __shfl_xor(s, 16);
        s += __shfl_xor(s, 32);
        inv[nt] = 1.0f / s;
    }
    // within-wave LDS RAW: drain ds_writes, pin ordering (rule 18)
    asm volatile("s_waitcnt lgkmcnt(0)" ::: "memory");
    __builtin_amdgcn_sched_barrier(0);

    // ---- PV: O^T[c][qy] = Σ_kn vraw^T[c][kn] · P'[qy][kn] ----
    f32x4 o[8][2];
#pragma unroll
    for (int mt = 0; mt < 8; ++mt)
#pragma unroll
        for (int nt = 0; nt < 2; ++nt) o[mt][nt] = (f32x4){0.f, 0.f, 0.f, 0.f};
#pragma unroll
    for (int i = 0; i < 7; ++i) {
        const int kxc = min(max(qx - 3 + i, 0), 31);
        bf16x8 pb[2];
#pragma unroll
        for (int nt = 0; nt < 2; ++nt)
            pb[nt] = *(const bf16x8*)&P[(16 * nt + l15) * PST + i * 32 + 8 * g];  // ds_read_b128
#pragma unroll
        for (int mt = 0; mt < 8; ++mt) {
            bf16x8 va = *(const bf16x8*)(vN + ((size_t)bt * CC + 16 * mt + l15) * NN + kxc * 32 + 8 * g);
#pragma unroll
            for (int nt = 0; nt < 2; ++nt)
                o[mt][nt] = __builtin_amdgcn_mfma_f32_16x16x32_bf16(va, pb[nt], o[mt][nt], 0, 0, 0);
        }
    }
#pragma unroll
    for (int mt = 0; mt < 8; ++mt) {
        f32x4 bv4 = *(const f32x4*)(bv + 16 * mt + 4 * g);
#pragma unroll
        for (int nt = 0; nt < 2; ++nt) {
            u16x4 ov;
#pragma unroll
            for (int r = 0; r < 4; ++r) ov[r] = f2b(o[mt][nt][r] * inv[nt] + bv4[r]);
            *(u16x4*)(attT + (btNN + qx * 32 + 16 * nt + l15) * CC + 16 * mt + 4 * g) = ov;
        }
    }
}

// ---------- kernel 4: fused output conv + LIF scan ----------
__global__ __launch_bounds__(128) void k_flif(
    const u16* __restrict__ attT, const u16* __restrict__ WfB,
    const float* __restrict__ bf, float* __restrict__ out)
{
    __shared__ float spk[128 * 36];
    const int t = threadIdx.x;
    const int n0b = blockIdx.x * 32;
    const int b = blockIdx.y;
    const int l = t & 63, w = t >> 6;
    const int l15 = l & 15, g = l >> 4;
    const int nloc = w * 16 + l15;
    f32x4 mem[8];
#pragma unroll
    for (int ot = 0; ot < 8; ++ot) mem[ot] = (f32x4){0.f, 0.f, 0.f, 0.f};

    for (int tt = 0; tt < 4; ++tt) {
        const u16* brow = attT + ((size_t)(b * 4 + tt) * NN + n0b + nloc) * CC;
        bf16x8 bfr[4];
#pragma unroll
        for (int kk = 0; kk < 4; ++kk)
            bfr[kk] = *(const bf16x8*)(brow + kk * 32 + g * 8);
#pragma unroll
        for (int ot = 0; ot < 8; ++ot) {
            f32x4 a = *(const f32x4*)(bf + 16 * ot + 4 * g);
#pragma unroll
            for (int kk = 0; kk < 4; ++kk)
                a = __builtin_amdgcn_mfma_f32_16x16x32_bf16(
                    *(const bf16x8*)(WfB + ((size_t)(ot * 4 + kk) * 64 + l) * 8),
                    bfr[kk], a, 0, 0, 0);
            f32x4 mv = mem[ot] * 0.5f + a;
#pragma unroll
            for (int r = 0; r < 4; ++r) {
                const float s = (mv[r] > 1.0f) ? 1.0f : 0.0f;
                spk[(16 * ot + 4 * g + r) * 36 + nloc] = s;
                if (mv[r] > 1.0f) mv[r] = 0.f;
            }
            mem[ot] = mv;
        }
        __syncthreads();
#pragma unroll
        for (int j = 0; j < 8; ++j) {
            const int i = t + 128 * j;
            const int row = i >> 3, n4 = (i & 7) * 4;
            *(float4*)(out + ((size_t)(b * 4 + tt) * CC + row) * NN + n0b + n4) =
                *(const float4*)&spk[row * 36 + n4];
        }
        __syncthreads();
    }
}

extern "C" void kernel_launch(void* const* d_in, const int* in_sizes, int n_in,
                              void* d_out, int out_size, void* d_ws, size_t ws_size,
                              hipStream_t stream) {
    (void)in_sizes; (void)n_in; (void)out_size; (void)ws_size;
    const float* edge = (const float*)d_in[0];
    const float* dvs  = (const float*)d_in[1];
    const float* We = (const float*)d_in[2];
    const float* be = (const float*)d_in[3];
    const float* Wd = (const float*)d_in[4];
    const float* bd = (const float*)d_in[5];
    const float* Wq = (const float*)d_in[6];
    const float* bq = (const float*)d_in[7];
    const float* Wk = (const float*)d_in[8];
    const float* bk = (const float*)d_in[9];
    const float* Wv = (const float*)d_in[10];
    const float* bv = (const float*)d_in[11];
    const float* Wf = (const float*)d_in[12];
    const float* bf = (const float*)d_in[13];
    float* out = (float*)d_out;

    const size_t S = (size_t)BTOT * NN * CC;  // 4.19M elems
    u16* qT   = (u16*)d_ws;
    u16* kT   = qT + S;
    u16* vN   = kT + S;
    u16* attT = vN + S;
    u16* WbAll = attT + S;                    // 6 * 16384 u16
    float* fbase = (float*)(WbAll + 6 * 16384);
    float* Wcomp = fbase;                     // 3 * 16384 f32
    float* cvec  = Wcomp + 3 * 16384;         // 3 * 128
    float* l2e   = cvec + 3 * CC;
    float* dens  = l2e + BTOT * NN;
    u16* WeB  = WbAll + 0 * 16384;
    u16* WdB  = WbAll + 1 * 16384;
    u16* WqeB = WbAll + 2 * 16384;
    u16* WkdB = WbAll + 3 * 16384;
    u16* WvdB = WbAll + 4 * 16384;
    u16* WfB  = WbAll + 5 * 16384;
    float* cq = cvec;
    float* ck = cvec + CC;
    float* cv = cvec + 2 * CC;

    k_comp<<<dim3(128, 3), 128, 0, stream>>>(Wq, Wk, Wv, We, Wd, be, bd, Wcomp, cvec);
    k_wcvt<<<48, 256, 0, stream>>>(We, Wd, Wcomp, Wcomp + 16384, Wcomp + 32768, Wf, WbAll);
    k_front<<<dim3(16, BTOT), 256, 0, stream>>>(edge, dvs, WeB, WdB, WqeB, WkdB, WvdB,
                                                be, bd, bq, cq, ck, cv, l2e, qT, kT, vN);
    k_dens<<<BTOT, 256, 0, stream>>>(l2e, dens);
    k_attn<<<256, 256, 0, stream>>>(qT, kT, vN, dens, bk, bv, attT);
    k_flif<<<dim3(32, 8), 128, 0, stream>>>(attT, WfB, bf, out);
}

// Round 7
// 68.946 us; speedup vs baseline: 5.5968x; 1.0359x over previous
//
#include <hip/hip_runtime.h>
#include <math.h>

#define CC 128   // channels
#define NN 1024  // H*W
#define BTOT 32  // B*T
#define CP 152   // k_front LDS row stride (bf16 elems)
#define PSTs 40  // P column-buffer row stride (u16): 80B = 5*16, b128-aligned
#define CPA 136  // att_lds row stride (u16): 272B = 17*16
#define CQS 36   // conv_q row stride (f32): 144B = 9*16

typedef unsigned short u16;
typedef u16 u16x8 __attribute__((ext_vector_type(8)));
typedef u16 u16x4 __attribute__((ext_vector_type(4)));
typedef __bf16 bf16x8 __attribute__((ext_vector_type(8)));
typedef float f32x4 __attribute__((ext_vector_type(4)));

__device__ __forceinline__ u16 f2b(float f) {
    unsigned int u = __float_as_uint(f);
    u += 0x7FFFu + ((u >> 16) & 1u);   // RNE
    return (u16)(u >> 16);
}
__device__ __forceinline__ float b2f(u16 u) {
    return __uint_as_float(((unsigned int)u) << 16);
}

// ---------- MFMA helpers ----------
// A-frag: lane l holds A[16*ot + (l&15)][32*kk + 8*(l>>4) + j], j=0..7.
// B-frag: lane l holds B[16*nt + (l&15)][32*kk + 8*(l>>4) + j].
// C/D: col = l&15 (B row), row = (l>>4)*4 + r (+16*ot) (A row).
__device__ __forceinline__ void loadB(const u16* brow, int g, bf16x8 bfr[4]) {
#pragma unroll
    for (int kk = 0; kk < 4; ++kk)
        bfr[kk] = *(const bf16x8*)(brow + kk * 32 + g * 8);
}
__device__ __forceinline__ bf16x8 ldA(const u16* __restrict__ WB, int ot, int kk, int l) {
    return *(const bf16x8*)(WB + ((size_t)(ot * 4 + kk) * 64 + l) * 8);
}

// ---------- kernel -1: compose weights (fp32): Wqe=Wq*We, Wkd=Wk*Wd, Wvd=Wv*Wd ----------
__global__ __launch_bounds__(128) void k_comp(
    const float* __restrict__ Wq, const float* __restrict__ Wk,
    const float* __restrict__ Wv, const float* __restrict__ We,
    const float* __restrict__ Wd, const float* __restrict__ be,
    const float* __restrict__ bd,
    float* __restrict__ Wcomp, float* __restrict__ cvec)
{
    const int mat = blockIdx.y, o = blockIdx.x, c = threadIdx.x;
    const float* A = (mat == 0) ? Wq : (mat == 1) ? Wk : Wv;
    const float* B = (mat == 0) ? We : Wd;
    const float* bv = (mat == 0) ? be : bd;
    float acc = 0.f;
    for (int m = 0; m < CC; ++m) acc += A[o * CC + m] * B[m * CC + c];
    Wcomp[(size_t)mat * 16384 + o * CC + c] = acc;
    if (c == 0) {
        float bacc = 0.f;
        for (int m = 0; m < CC; ++m) bacc += A[o * CC + m] * bv[m];
        cvec[mat * CC + o] = bacc;
    }
}

// ---------- kernel 0: pack 6 weight matrices into bf16 frag order ----------
__global__ __launch_bounds__(256) void k_wcvt(
    const float* __restrict__ W0, const float* __restrict__ W1,
    const float* __restrict__ W2, const float* __restrict__ W3,
    const float* __restrict__ W4, const float* __restrict__ W5,
    u16* __restrict__ out)
{
    const int gid = blockIdx.x * 256 + threadIdx.x;  // 6*2048
    const int wi = gid >> 11, rem = gid & 2047;
    const float* W = (wi == 0) ? W0 : (wi == 1) ? W1 : (wi == 2) ? W2
                   : (wi == 3) ? W3 : (wi == 4) ? W4 : W5;
    const int ot = rem >> 8, kk = (rem >> 6) & 3, l = rem & 63;
    const int row = ot * 16 + (l & 15), col = kk * 32 + (l >> 4) * 8;
    float4 a = *(const float4*)(W + row * CC + col);
    float4 b = *(const float4*)(W + row * CC + col + 4);
    u16x8 u;
    u[0] = f2b(a.x); u[1] = f2b(a.y); u[2] = f2b(a.z); u[3] = f2b(a.w);
    u[4] = f2b(b.x); u[5] = f2b(b.y); u[6] = f2b(b.z); u[7] = f2b(b.w);
    *(u16x8*)(out + (size_t)wi * 16384 + ((size_t)(ot * 4 + kk) * 64 + l) * 8) = u;
}

// ---------- kernel 1: front — 5 independent MFMA GEMMs from staged inputs ----------
__global__ __launch_bounds__(256) void k_front(
    const float* __restrict__ edge, const float* __restrict__ dvs,
    const u16* __restrict__ WeB, const u16* __restrict__ WdB,
    const u16* __restrict__ WqeB, const u16* __restrict__ WkdB,
    const u16* __restrict__ WvdB,
    const float* __restrict__ be, const float* __restrict__ bd,
    const float* __restrict__ bq,
    const float* __restrict__ cq, const float* __restrict__ ck,
    const float* __restrict__ cv,
    float* __restrict__ l2e_out,
    u16* __restrict__ qT, u16* __restrict__ kT, u16* __restrict__ vN)
{
    __shared__ u16 bufA[64 * CP];
    __shared__ u16 bufB[64 * CP];
    const int t = threadIdx.x;
    const int bt = blockIdx.y;
    const int n0b = blockIdx.x * 64;
    const float* eb = edge + (size_t)bt * CC * NN + n0b;
    const float* db = dvs + (size_t)bt * CC * NN + n0b;

    // stage: transpose [c][n] fp32 -> [n][c] bf16
#pragma unroll
    for (int j = 0; j < 2; ++j) {
        const int i = t + 256 * j;
        const int c4 = i >> 4, p = i & 15;
        float4 e[4], d[4];
#pragma unroll
        for (int m = 0; m < 4; ++m) {
            e[m] = *(const float4*)(eb + (size_t)(4 * c4 + m) * NN + 4 * p);
            d[m] = *(const float4*)(db + (size_t)(4 * c4 + m) * NN + 4 * p);
        }
#pragma unroll
        for (int n = 0; n < 4; ++n) {
            u16x4 ue, ud;
            ue[0] = f2b(((const float*)&e[0])[n]); ud[0] = f2b(((const float*)&d[0])[n]);
            ue[1] = f2b(((const float*)&e[1])[n]); ud[1] = f2b(((const float*)&d[1])[n]);
            ue[2] = f2b(((const float*)&e[2])[n]); ud[2] = f2b(((const float*)&d[2])[n]);
            ue[3] = f2b(((const float*)&e[3])[n]); ud[3] = f2b(((const float*)&d[3])[n]);
            *(u16x4*)&bufA[(4 * p + n) * CP + 4 * c4] = ue;
            *(u16x4*)&bufB[(4 * p + n) * CP + 4 * c4] = ud;
        }
    }
    __syncthreads();

    const int l = t & 63, w = t >> 6;
    const int l15 = l & 15, g = l >> 4;
    const int nloc = w * 16 + l15;
    const size_t gn = (size_t)bt * NN + n0b + nloc;

    bf16x8 bfrE[4], bfrD[4];
    loadB(bufA + nloc * CP, g, bfrE);
    loadB(bufB + nloc * CP, g, bfrD);

    // --- ef/df accumulators (stats only, never materialized) ---
    f32x4 aE[8], aD[8];
#pragma unroll
    for (int ot = 0; ot < 8; ++ot) {
        aE[ot] = *(const f32x4*)(be + 16 * ot + 4 * g);
        aD[ot] = *(const f32x4*)(bd + 16 * ot + 4 * g);
    }
#pragma unroll
    for (int ot = 0; ot < 8; ++ot)
#pragma unroll
        for (int kk = 0; kk < 4; ++kk) {
            aE[ot] = __builtin_amdgcn_mfma_f32_16x16x32_bf16(ldA(WeB, ot, kk, l), bfrE[kk], aE[ot], 0, 0, 0);
            aD[ot] = __builtin_amdgcn_mfma_f32_16x16x32_bf16(ldA(WdB, ot, kk, l), bfrD[kk], aD[ot], 0, 0, 0);
        }
    float s2e = 0.f, s2d = 0.f, sed = 0.f;
#pragma unroll
    for (int ot = 0; ot < 8; ++ot)
#pragma unroll
        for (int r = 0; r < 4; ++r) {
            const float fe = aE[ot][r], fd = aD[ot][r];
            s2e += fe * fe; s2d += fd * fd; sed += fe * fd;
        }
    s2e += __shfl_xor(s2e, 16); s2e += __shfl_xor(s2e, 32);
    s2d += __shfl_xor(s2d, 16); s2d += __shfl_xor(s2d, 32);
    sed += __shfl_xor(sed, 16); sed += __shfl_xor(sed, 32);
    const float le = sqrtf(s2e), ld = sqrtf(s2d);
    const float sim = (sed / ((le + 1e-6f) * (ld + 1e-6f)) + 1.0f) * 0.5f;
    if (g == 0) l2e_out[gn] = le;

    // --- q = sim*(Wqe*e + cq) + bq ---
    {
        f32x4 aQ[8];
#pragma unroll
        for (int ot = 0; ot < 8; ++ot) aQ[ot] = *(const f32x4*)(cq + 16 * ot + 4 * g);
#pragma unroll
        for (int ot = 0; ot < 8; ++ot)
#pragma unroll
            for (int kk = 0; kk < 4; ++kk)
                aQ[ot] = __builtin_amdgcn_mfma_f32_16x16x32_bf16(ldA(WqeB, ot, kk, l), bfrE[kk], aQ[ot], 0, 0, 0);
#pragma unroll
        for (int ot = 0; ot < 8; ++ot) {
            f32x4 b4 = *(const f32x4*)(bq + 16 * ot + 4 * g);
            u16x4 u;
#pragma unroll
            for (int r = 0; r < 4; ++r) u[r] = f2b(sim * aQ[ot][r] + b4[r]);
            *(u16x4*)(qT + gn * CC + 16 * ot + 4 * g) = u;
        }
    }
    // --- kraw = Wkd*d + ck ---
    {
        f32x4 aK[8];
#pragma unroll
        for (int ot = 0; ot < 8; ++ot) aK[ot] = *(const f32x4*)(ck + 16 * ot + 4 * g);
#pragma unroll
        for (int ot = 0; ot < 8; ++ot)
#pragma unroll
            for (int kk = 0; kk < 4; ++kk)
                aK[ot] = __builtin_amdgcn_mfma_f32_16x16x32_bf16(ldA(WkdB, ot, kk, l), bfrD[kk], aK[ot], 0, 0, 0);
#pragma unroll
        for (int ot = 0; ot < 8; ++ot) {
            u16x4 u;
#pragma unroll
            for (int r = 0; r < 4; ++r) u[r] = f2b(aK[ot][r]);
            *(u16x4*)(kT + gn * CC + 16 * ot + 4 * g) = u;
        }
    }
    // --- vraw = Wvd*d + cv ; channel-major vN[c][n] via LDS transpose ---
    {
        f32x4 aV[8];
#pragma unroll
        for (int ot = 0; ot < 8; ++ot) aV[ot] = *(const f32x4*)(cv + 16 * ot + 4 * g);
#pragma unroll
        for (int ot = 0; ot < 8; ++ot)
#pragma unroll
            for (int kk = 0; kk < 4; ++kk)
                aV[ot] = __builtin_amdgcn_mfma_f32_16x16x32_bf16(ldA(WvdB, ot, kk, l), bfrD[kk], aV[ot], 0, 0, 0);
        __syncthreads();  // bufA reads (loadB) all done -> safe to reuse
        u16* bufT = bufA; // [128][72] u16 = 9216 <= 64*CP
#pragma unroll
        for (int ot = 0; ot < 8; ++ot)
#pragma unroll
            for (int r = 0; r < 4; ++r)
                bufT[(16 * ot + 4 * g + r) * 72 + nloc] = f2b(aV[ot][r]);
        __syncthreads();
#pragma unroll
        for (int p = 0; p < 4; ++p) {
            const int idx = t + 256 * p;
            const int c = idx >> 3, n8 = (idx & 7) * 8;
            *(u16x8*)(vN + ((size_t)bt * CC + c) * NN + n0b + n8) =
                *(const u16x8*)&bufT[c * 72 + n8];
        }
    }
}

// ---------- kernel 2: spatial softmax of l2e -> density ----------
__global__ __launch_bounds__(256) void k_dens(const float* __restrict__ l2e,
                                              float* __restrict__ dens)
{
    __shared__ float red1[4];
    __shared__ float red2[4];
    const int bt = blockIdx.x, t = threadIdx.x;
    const int lane = t & 63, wid = t >> 6;
    const float* x = l2e + (size_t)bt * NN;
    float v[4], m = -1e30f;
#pragma unroll
    for (int i = 0; i < 4; ++i) { v[i] = x[t + 256 * i]; m = fmaxf(m, v[i]); }
#pragma unroll
    for (int off = 32; off >= 1; off >>= 1) m = fmaxf(m, __shfl_xor(m, off));
    if (lane == 0) red1[wid] = m;
    __syncthreads();
    m = fmaxf(fmaxf(red1[0], red1[1]), fmaxf(red1[2], red1[3]));
    float e[4], s = 0.f;
#pragma unroll
    for (int i = 0; i < 4; ++i) { e[i] = expf(v[i] - m); s += e[i]; }
#pragma unroll
    for (int off = 32; off >= 1; off >>= 1) s += __shfl_xor(s, off);
    if (lane == 0) red2[wid] = s;
    __syncthreads();
    s = red2[0] + red2[1] + red2[2] + red2[3];
    const float scale = 1024.0f / s;
#pragma unroll
    for (int i = 0; i < 4; ++i) dens[(size_t)bt * NN + t + 256 * i] = e[i] * scale;
}

// ---------- kernel 3: FUSED attention + output conv + LIF ----------
// block = (b, qx); wave w = time step tt; bt = b*4+w.
// Per wave: interleaved per-kx {QK^T -> P' column -> PV}, then O -> att_lds
// (transpose), conv Wf from LDS B-frags, LIF via LDS exchange in 4 c-quarters.
__global__ __launch_bounds__(256) void k_attnf(
    const u16* __restrict__ qT, const u16* __restrict__ kT,
    const u16* __restrict__ vN, const float* __restrict__ dens,
    const float* __restrict__ bk, const float* __restrict__ bv,
    const u16* __restrict__ WfB, const float* __restrict__ bf,
    float* __restrict__ out)
{
    __shared__ u16 lds_u16[26624];  // 53248 B total
    const int t = threadIdx.x;
    const int id = blockIdx.x;
    const int b = id & 7, qx = id >> 3;   // XCD x owns b = x (L2 locality)
    const int w = t >> 6;
    const int bt = b * 4 + w;
    const int l = t & 63, l15 = l & 15, g = l >> 4;
    u16* att = lds_u16;                                   // [4][32][CPA]
    float* convq = (float*)(lds_u16 + 17408);             // [4][32][CQS] f32
    u16* P = lds_u16 + w * 32 * PSTs;                     // overlays att region
    const size_t btNN = (size_t)bt * NN;
    const float invsq = 0.08838834764831843f;  // 1/sqrt(128)

    // q fragments
    u16x8 ql[2][4];
#pragma unroll
    for (int nt = 0; nt < 2; ++nt)
#pragma unroll
        for (int kk = 0; kk < 4; ++kk)
            ql[nt][kk] = *(const u16x8*)(qT + (btNN + qx * 32 + 16 * nt + l15) * CC + 32 * kk + 8 * g);

    // qbk[nt] = q[qy]·bk
    float qbk[2] = {0.f, 0.f};
#pragma unroll
    for (int kk = 0; kk < 4; ++kk) {
        f32x4 b0 = *(const f32x4*)(bk + 32 * kk + 8 * g);
        f32x4 b1 = *(const f32x4*)(bk + 32 * kk + 8 * g + 4);
#pragma unroll
        for (int nt = 0; nt < 2; ++nt)
#pragma unroll
            for (int j = 0; j < 4; ++j) {
                qbk[nt] += b2f(ql[nt][kk][j]) * b0[j];
                qbk[nt] += b2f(ql[nt][kk][4 + j]) * b1[j];
            }
    }
#pragma unroll
    for (int nt = 0; nt < 2; ++nt) {
        qbk[nt] += __shfl_xor(qbk[nt], 16);
        qbk[nt] += __shfl_xor(qbk[nt], 32);
    }

    // ---- interleaved QK^T / P' / PV over the 7 kx columns ----
    float ssum[2] = {0.f, 0.f};
    f32x4 o[8][2];
#pragma unroll
    for (int mt = 0; mt < 8; ++mt)
#pragma unroll
        for (int nt = 0; nt < 2; ++nt) o[mt][nt] = (f32x4){0.f, 0.f, 0.f, 0.f};

#pragma unroll
    for (int i = 0; i < 7; ++i) {
        const int kxr = qx - 3 + i;
        const int kxc = min(max(kxr, 0), 31);
        const bool cval = (kxr == kxc);
        f32x4 acc[2][2];
#pragma unroll
        for (int mt = 0; mt < 2; ++mt)
#pragma unroll
            for (int nt = 0; nt < 2; ++nt) acc[mt][nt] = (f32x4){0.f, 0.f, 0.f, 0.f};
#pragma unroll
        for (int kk = 0; kk < 4; ++kk)
#pragma unroll
            for (int mt = 0; mt < 2; ++mt) {
                bf16x8 ka = *(const bf16x8*)(kT + (btNN + kxc * 32 + 16 * mt + l15) * CC + 32 * kk + 8 * g);
#pragma unroll
                for (int nt = 0; nt < 2; ++nt)
                    acc[mt][nt] = __builtin_amdgcn_mfma_f32_16x16x32_bf16(
                        ka, __builtin_bit_cast(bf16x8, ql[nt][kk]), acc[mt][nt], 0, 0, 0);
            }
#pragma unroll
        for (int mt = 0; mt < 2; ++mt) {
            f32x4 d4 = *(const f32x4*)(dens + btNN + kxc * 32 + 16 * mt + 4 * g);
#pragma unroll
            for (int nt = 0; nt < 2; ++nt) {
                const int qyv = l15 + 16 * nt;
                u16x4 pw;
#pragma unroll
                for (int r = 0; r < 4; ++r) {
                    const float s = (d4[r] * acc[mt][nt][r] + qbk[nt]) * invsq;
                    const int ky = 16 * mt + 4 * g + r;
                    const int dy = ky - qyv;
                    const bool vld = cval && (dy >= -3) && (dy <= 3);
                    const float e = vld ? __expf(s) : 0.f;
                    ssum[nt] += e;
                    pw[r] = f2b(e * d4[r]);
                }
                *(u16x4*)&P[qyv * PSTs + 16 * mt + 4 * g] = pw;
            }
        }
        asm volatile("s_waitcnt lgkmcnt(0)" ::: "memory");
        __builtin_amdgcn_sched_barrier(0);
        bf16x8 pb[2];
#pragma unroll
        for (int nt = 0; nt < 2; ++nt)
            pb[nt] = *(const bf16x8*)&P[(16 * nt + l15) * PSTs + 8 * g];
#pragma unroll
        for (int mt = 0; mt < 8; ++mt) {
            bf16x8 va = *(const bf16x8*)(vN + ((size_t)bt * CC + 16 * mt + l15) * NN + kxc * 32 + 8 * g);
#pragma unroll
            for (int nt = 0; nt < 2; ++nt)
                o[mt][nt] = __builtin_amdgcn_mfma_f32_16x16x32_bf16(va, pb[nt], o[mt][nt], 0, 0, 0);
        }
    }
    float inv[2];
#pragma unroll
    for (int nt = 0; nt < 2; ++nt) {
        float s = ssum[nt];
        s += __shfl_xor(s, 16);
        s += __shfl_xor(s, 32);
        inv[nt] = 1.0f / s;
    }

    __syncthreads();  // all P reads done before att overwrites the region

    // ---- O (col=qy,row=c) -> att_lds[w][n][c] bf16 (incl. inv scale + bv) ----
    u16* attw = att + w * 32 * CPA;
#pragma unroll
    for (int mt = 0; mt < 8; ++mt) {
        f32x4 bv4 = *(const f32x4*)(bv + 16 * mt + 4 * g);
#pragma unroll
        for (int nt = 0; nt < 2; ++nt) {
            u16x4 ov;
#pragma unroll
            for (int r = 0; r < 4; ++r) ov[r] = f2b(o[mt][nt][r] * inv[nt] + bv4[r]);
            *(u16x4*)&attw[(16 * nt + l15) * CPA + 16 * mt + 4 * g] = ov;
        }
    }
    asm volatile("s_waitcnt lgkmcnt(0)" ::: "memory");
    __builtin_amdgcn_sched_barrier(0);

    // conv B-frags from own wave's att slice
    bf16x8 cb[4][2];
#pragma unroll
    for (int kk = 0; kk < 4; ++kk)
#pragma unroll
        for (int nt = 0; nt < 2; ++nt)
            cb[kk][nt] = *(const bf16x8*)&attw[(16 * nt + l15) * CPA + 32 * kk + 8 * g];

    // ---- conv + LIF in 4 c-quarters ----
    const int cl = t >> 3, n4 = (t & 7) * 4;  // LIF ownership
#pragma unroll
    for (int cr = 0; cr < 4; ++cr) {
#pragma unroll
        for (int oi = 0; oi < 2; ++oi) {
            const int ot = 2 * cr + oi;
            f32x4 ca[2];
#pragma unroll
            for (int nt = 0; nt < 2; ++nt) ca[nt] = *(const f32x4*)(bf + 16 * ot + 4 * g);
#pragma unroll
            for (int kk = 0; kk < 4; ++kk) {
                bf16x8 afr = ldA(WfB, ot, kk, l);
#pragma unroll
                for (int nt = 0; nt < 2; ++nt)
                    ca[nt] = __builtin_amdgcn_mfma_f32_16x16x32_bf16(afr, cb[kk][nt], ca[nt], 0, 0, 0);
            }
#pragma unroll
            for (int nt = 0; nt < 2; ++nt)
#pragma unroll
                for (int r = 0; r < 4; ++r)
                    convq[w * 32 * CQS + (16 * oi + 4 * g + r) * CQS + 16 * nt + l15] = ca[nt][r];
        }
        __syncthreads();
        // LIF over tt for c = 32*cr + cl, n = qx*32 + n4..n4+3
        f32x4 mem = {0.f, 0.f, 0.f, 0.f};
#pragma unroll
        for (int tt = 0; tt < 4; ++tt) {
            f32x4 x = *(const f32x4*)&convq[tt * 32 * CQS + cl * CQS + n4];
            f32x4 mv = mem * 0.5f + x;
            float4 sp;
            sp.x = (mv[0] > 1.0f) ? 1.0f : 0.0f; if (mv[0] > 1.0f) mv[0] = 0.f;
            sp.y = (mv[1] > 1.0f) ? 1.0f : 0.0f; if (mv[1] > 1.0f) mv[1] = 0.f;
            sp.z = (mv[2] > 1.0f) ? 1.0f : 0.0f; if (mv[2] > 1.0f) mv[2] = 0.f;
            sp.w = (mv[3] > 1.0f) ? 1.0f : 0.0f; if (mv[3] > 1.0f) mv[3] = 0.f;
            *(float4*)(out + ((size_t)(b * 4 + tt) * CC + 32 * cr + cl) * NN + qx * 32 + n4) = sp;
            mem = mv;
        }
        __syncthreads();
    }
}

extern "C" void kernel_launch(void* const* d_in, const int* in_sizes, int n_in,
                              void* d_out, int out_size, void* d_ws, size_t ws_size,
                              hipStream_t stream) {
    (void)in_sizes; (void)n_in; (void)out_size; (void)ws_size;
    const float* edge = (const float*)d_in[0];
    const float* dvs  = (const float*)d_in[1];
    const float* We = (const float*)d_in[2];
    const float* be = (const float*)d_in[3];
    const float* Wd = (const float*)d_in[4];
    const float* bd = (const float*)d_in[5];
    const float* Wq = (const float*)d_in[6];
    const float* bq = (const float*)d_in[7];
    const float* Wk = (const float*)d_in[8];
    const float* bk = (const float*)d_in[9];
    const float* Wv = (const float*)d_in[10];
    const float* bv = (const float*)d_in[11];
    const float* Wf = (const float*)d_in[12];
    const float* bf = (const float*)d_in[13];
    float* out = (float*)d_out;

    const size_t S = (size_t)BTOT * NN * CC;  // 4.19M elems
    u16* qT   = (u16*)d_ws;
    u16* kT   = qT + S;
    u16* vN   = kT + S;
    u16* WbAll = vN + S;                      // 6 * 16384 u16
    float* fbase = (float*)(WbAll + 6 * 16384);
    float* Wcomp = fbase;                     // 3 * 16384 f32
    float* cvec  = Wcomp + 3 * 16384;         // 3 * 128
    float* l2e   = cvec + 3 * CC;
    float* dens  = l2e + BTOT * NN;
    u16* WeB  = WbAll + 0 * 16384;
    u16* WdB  = WbAll + 1 * 16384;
    u16* WqeB = WbAll + 2 * 16384;
    u16* WkdB = WbAll + 3 * 16384;
    u16* WvdB = WbAll + 4 * 16384;
    u16* WfB  = WbAll + 5 * 16384;
    float* cq = cvec;
    float* ck = cvec + CC;
    float* cv = cvec + 2 * CC;

    k_comp<<<dim3(128, 3), 128, 0, stream>>>(Wq, Wk, Wv, We, Wd, be, bd, Wcomp, cvec);
    k_wcvt<<<48, 256, 0, stream>>>(We, Wd, Wcomp, Wcomp + 16384, Wcomp + 32768, Wf, WbAll);
    k_front<<<dim3(16, BTOT), 256, 0, stream>>>(edge, dvs, WeB, WdB, WqeB, WkdB, WvdB,
                                                be, bd, bq, cq, ck, cv, l2e, qT, kT, vN);
    k_dens<<<BTOT, 256, 0, stream>>>(l2e, dens);
    k_attnf<<<256, 256, 0, stream>>>(qT, kT, vN, dens, bk, bv, WfB, bf, out);
}